// Round 2
// baseline (6570.909 us; speedup 1.0000x reference)
//
#include <hip/hip_runtime.h>

#define NB 16384
#define NT 1024

// ---- tanh LDS table: 6144 entries x float2(value, secant slope) = 48 KB ----
// Domain |x| in [0, TMAX]; index scale TSCALE folded into W1/b1/W2/b2 (where
// 2*log2(e) used to be in r11). Interp err <= f''max*dx^2/8 ~= 2.1e-7 (+ node
// rounding 6e-8) — below the f16-split noise floor that scored absmax 0.0078.
#define NE 6144
#define TMAX 9.0f
#define TSCALE (6143.0f / 9.0f)

typedef _Float16 h8  __attribute__((ext_vector_type(8)));
typedef __fp16   g2  __attribute__((ext_vector_type(2)));   // cvt_pkrtz result type
typedef float    f4  __attribute__((ext_vector_type(4)));

// AS4 scalar loads for wave-uniform data (ts).
typedef __attribute__((address_space(4))) const float cfloat;
static __device__ __forceinline__ const cfloat* as_const(const float* p) {
  return (const cfloat*)(unsigned long long)p;
}

union H8U { h8 v; g2 p[4]; };  // type-pun: 4 packed pairs <-> one MFMA operand

// Pin into VGPR (generous budget required: min_waves=1; r7 proved tight bounds
// re-trigger in-loop rematerialization of the W2 loads -> 34.8 GB FETCH).
#define PINV(x)  asm volatile("" : "+v"(x))

// Table tanh: t is the preact in table-index units (TSCALE pre-folded into
// weights). Only bog-standard ops: fabs/fmin/cvt/sub/ds_read_b64/fma/bitops.
// fr = a - (float)i is exact (a >= 0, i = trunc(a)). Output bounded in (-1,1).
static __device__ __forceinline__ float tanh_tab(float t, const float2* __restrict__ tab) {
  float a = __builtin_fabsf(t);                 // v_and
  a = __builtin_fminf(a, (float)(NE - 1));      // v_min (also tames Inf/NaN)
  const int   i  = (int)a;                      // v_cvt_i32_f32 (trunc, a>=0)
  const float fr = a - (float)i;                // v_cvt_f32_i32 + v_sub, exact
  const float2 e = tab[i];                      // ds_read_b64 gather
  const float h  = __builtin_fmaf(fr, e.y, e.x);
  const unsigned hb = __builtin_bit_cast(unsigned, h) |
                      (__builtin_bit_cast(unsigned, t) & 0x80000000u);  // sign
  return __builtin_bit_cast(float, hb);
}

// ---- Round 13 = r11 (proven) + LDS tanh table ONLY ----
// r12 failed (absmax 3023 = wrong-but-bounded field => logic bug, not
// precision). r12's unproven primitives (permlane qsum, f4-PINV, fractf) are
// reverted to r11's proven forms; the table is the isolated change. Issue
// model: 2112 cyc/wave-eval, ~1024 of it = 64 trans ops (v_exp+v_rcp at
// ~16cyc/wave). Table tanh = ~9 full-rate VALU + 1 b64 gather on the idle
// LDS pipe => predict ~-550 cyc/eval.
__global__ __launch_bounds__(256, 1)
void node_step_kernel(const float* __restrict__ y0,
                      const float* __restrict__ ts,
                      const float* __restrict__ W1,
                      const float* __restrict__ b1,
                      const float* __restrict__ W2,
                      const float* __restrict__ b2,
                      const float* __restrict__ W3,
                      const float* __restrict__ b3,
                      float* __restrict__ out)
{
  __shared__ float2 tab[NE];   // 48 KB (1 block/CU; 160 KB available)
  {
    const float dx = TMAX / (float)(NE - 1);
    for (int i = (int)threadIdx.x; i < NE; i += 256) {
      const float v0 = tanhf((float)i * dx);
      const float v1 = tanhf((float)(i + 1) * dx);   // i=NE-1 slope unused (fr==0)
      tab[i] = make_float2(v0, v1 - v0);
    }
  }

  const int lane = (int)(threadIdx.x & 63);
  const int wv   = (int)(threadIdx.x >> 6);   // 0..3
  const int col  = lane & 15;                 // batch column within wave
  const int quad = lane >> 4;
  const int gb   = (int)blockIdx.x * 64 + wv * 16 + col;

  // ---- init: W2 A-fragments (x TSCALE), hi/lo f16, as pinned h8 ----
  // A-frag (HW-verified r5/r6): A[m = lane&15][k = quad*8 + j]; k-step adds 32.
  h8 Ah[4][2], Al[4][2];                      // [mtile][kstep]
#pragma unroll
  for (int mt = 0; mt < 4; ++mt) {
    const int m = mt * 16 + col;
#pragma unroll
    for (int ks = 0; ks < 2; ++ks) {
      const float* wp = W2 + m * 64 + ks * 32 + quad * 8;
      H8U hu, lu;
#pragma unroll
      for (int p = 0; p < 4; ++p) {
        const float x0 = wp[2*p]     * TSCALE;
        const float x1 = wp[2*p + 1] * TSCALE;
        const g2 hi = __builtin_amdgcn_cvt_pkrtz(x0, x1);
        hu.p[p] = hi;
        lu.p[p] = __builtin_amdgcn_cvt_pkrtz(x0 - (float)hi.x, x1 - (float)hi.y);
      }
      Ah[mt][ks] = hu.v;  PINV(Ah[mt][ks]);
      Al[mt][ks] = lu.v;  PINV(Al[mt][ks]);
    }
  }

  // b2 (x TSCALE, acc init) and W3 rows in C/D layout (HW-verified:
  // col = lane&15, row = mt*16 + quad*4 + reg). Pinned. (r11 verbatim form.)
  float accb[4][4], w30[4][4], w31[4][4];
#pragma unroll
  for (int mt = 0; mt < 4; ++mt) {
#pragma unroll
    for (int r = 0; r < 4; ++r) {
      const int j2 = mt * 16 + quad * 4 + r;
      accb[mt][r] = b2[j2] * TSCALE;  PINV(accb[mt][r]);
      w30[mt][r]  = W3[j2];           PINV(w30[mt][r]);
      w31[mt][r]  = W3[64 + j2];      PINV(w31[mt][r]);
    }
  }

  // L1 weights (x TSCALE) for exactly the 16 rows this lane's B-fragments
  // cover: i<8 -> row = quad*8+i (kstep0); i>=8 -> row = 32+quad*8+(i-8).
  float w1a[16], w1b[16], b1r[16];
#pragma unroll
  for (int i = 0; i < 16; ++i) {
    const int row = (i < 8) ? (quad * 8 + i) : (32 + quad * 8 + (i - 8));
    w1a[i] = W1[2 * row]     * TSCALE;  PINV(w1a[i]);
    w1b[i] = W1[2 * row + 1] * TSCALE;  PINV(w1b[i]);
    b1r[i] = b1[row]         * TSCALE;  PINV(b1r[i]);
  }
  const cfloat* tsc = as_const(ts);
  const float b30 = b3[0], b31 = b3[1];

  float yx = y0[2 * gb], yy = y0[2 * gb + 1];

  float2* __restrict__ outv = (float2*)out;
  if (quad == 0) outv[gb] = make_float2(yx, yy);   // SaveAt includes t0

  __syncthreads();   // table ready before first EVAL

  const float A21 = (float)(1.0/5.0);
  const float A31 = (float)(3.0/40.0),  A32 = (float)(9.0/40.0);
  const float A41 = (float)(44.0/45.0), A42 = (float)(-56.0/15.0), A43 = (float)(32.0/9.0);
  const float A51 = (float)(19372.0/6561.0), A52 = (float)(-25360.0/2187.0),
              A53 = (float)(64448.0/6561.0), A54 = (float)(-212.0/729.0);
  const float A61 = (float)(9017.0/3168.0), A62 = (float)(-355.0/33.0),
              A63 = (float)(46732.0/5247.0), A64 = (float)(49.0/176.0),
              A65 = (float)(-5103.0/18656.0);
  const float BB1 = (float)(35.0/384.0), BB3 = (float)(500.0/1113.0),
              BB4 = (float)(125.0/192.0), BB5 = (float)(-2187.0/6784.0),
              BB6 = (float)(11.0/84.0);

  float k1x,k1y,k2x,k2y,k3x,k3y,k4x,k4y,k5x,k5y,k6x,k6y;

  for (int t = 0; t < NT - 1; ++t) {
    const float dt = tsc[t + 1] - tsc[t];

    auto EVAL = [&](float ysx, float ysy, float& kx, float& ky) {
      // ---- L1: 16 h1 rows (pre-scaled weights -> 2 fma + table tanh) ----
      float hv[16];
#pragma unroll
      for (int i = 0; i < 16; ++i)
        hv[i] = tanh_tab(fmaf(w1a[i], ysx, fmaf(w1b[i], ysy, b1r[i])), tab);

      // pair-pack into B-fragments via v_cvt_pkrtz (hi) + residual pack (lo)
      H8U BH0, BL0, BH1, BL1;
#pragma unroll
      for (int p = 0; p < 4; ++p) {
        const g2 h0 = __builtin_amdgcn_cvt_pkrtz(hv[2*p], hv[2*p+1]);
        BH0.p[p] = h0;
        BL0.p[p] = __builtin_amdgcn_cvt_pkrtz(hv[2*p]   - (float)h0.x,
                                              hv[2*p+1] - (float)h0.y);
        const g2 h1 = __builtin_amdgcn_cvt_pkrtz(hv[8+2*p], hv[9+2*p]);
        BH1.p[p] = h1;
        BL1.p[p] = __builtin_amdgcn_cvt_pkrtz(hv[8+2*p] - (float)h1.x,
                                              hv[9+2*p] - (float)h1.y);
      }

      // ---- L2: 4 m-tiles x (2 k-steps x 3 split products) MFMA ----
      float p0 = 0.0f, p1 = 0.0f;
#pragma unroll
      for (int mt = 0; mt < 4; ++mt) {
        f4 c = { accb[mt][0], accb[mt][1], accb[mt][2], accb[mt][3] };
        c = __builtin_amdgcn_mfma_f32_16x16x32_f16(Al[mt][0], BH0.v, c, 0, 0, 0);
        c = __builtin_amdgcn_mfma_f32_16x16x32_f16(Ah[mt][0], BL0.v, c, 0, 0, 0);
        c = __builtin_amdgcn_mfma_f32_16x16x32_f16(Ah[mt][0], BH0.v, c, 0, 0, 0);
        c = __builtin_amdgcn_mfma_f32_16x16x32_f16(Al[mt][1], BH1.v, c, 0, 0, 0);
        c = __builtin_amdgcn_mfma_f32_16x16x32_f16(Ah[mt][1], BL1.v, c, 0, 0, 0);
        c = __builtin_amdgcn_mfma_f32_16x16x32_f16(Ah[mt][1], BH1.v, c, 0, 0, 0);
        // ---- L3 partials: table tanh (scale folded into W2/b2) + W3 ----
#pragma unroll
        for (int r = 0; r < 4; ++r) {
          const float h2 = tanh_tab(c[r], tab);
          p0 = fmaf(w30[mt][r], h2, p0);
          p1 = fmaf(w31[mt][r], h2, p1);
        }
      }
      // quad butterfly: lanes col, col^16, col^32, col^48 hold the 4 row-quarters
      p0 += __shfl_xor(p0, 16); p1 += __shfl_xor(p1, 16);
      p0 += __shfl_xor(p0, 32); p1 += __shfl_xor(p1, 32);
      kx = p0 + b30;
      ky = p1 + b31;
    };

    EVAL(yx, yy, k1x, k1y);
    EVAL(fmaf(dt, A21 * k1x, yx), fmaf(dt, A21 * k1y, yy), k2x, k2y);
    {
      float cx = fmaf(A32, k2x, A31 * k1x);
      float cy = fmaf(A32, k2y, A31 * k1y);
      EVAL(fmaf(dt, cx, yx), fmaf(dt, cy, yy), k3x, k3y);
    }
    {
      float cx = fmaf(A43, k3x, fmaf(A42, k2x, A41 * k1x));
      float cy = fmaf(A43, k3y, fmaf(A42, k2y, A41 * k1y));
      EVAL(fmaf(dt, cx, yx), fmaf(dt, cy, yy), k4x, k4y);
    }
    {
      float cx = fmaf(A54, k4x, fmaf(A53, k3x, fmaf(A52, k2x, A51 * k1x)));
      float cy = fmaf(A54, k4y, fmaf(A53, k3y, fmaf(A52, k2y, A51 * k1y)));
      EVAL(fmaf(dt, cx, yx), fmaf(dt, cy, yy), k5x, k5y);
    }
    {
      float cx = fmaf(A65, k5x, fmaf(A64, k4x, fmaf(A63, k3x, fmaf(A62, k2x, A61 * k1x))));
      float cy = fmaf(A65, k5y, fmaf(A64, k4y, fmaf(A63, k3y, fmaf(A62, k2y, A61 * k1y))));
      EVAL(fmaf(dt, cx, yx), fmaf(dt, cy, yy), k6x, k6y);
    }
    {
      float cx = fmaf(BB6, k6x, fmaf(BB5, k5x, fmaf(BB4, k4x, fmaf(BB3, k3x, BB1 * k1x))));
      float cy = fmaf(BB6, k6y, fmaf(BB5, k5y, fmaf(BB4, k4y, fmaf(BB3, k3y, BB1 * k1y))));
      yx = fmaf(dt, cx, yx);
      yy = fmaf(dt, cy, yy);
    }
    if (quad == 0) outv[(t + 1) * NB + gb] = make_float2(yx, yy);
  }
}

extern "C" void kernel_launch(void* const* d_in, const int* in_sizes, int n_in,
                              void* d_out, int out_size, void* d_ws, size_t ws_size,
                              hipStream_t stream) {
  const float* y0 = (const float*)d_in[0];
  const float* ts = (const float*)d_in[1];
  const float* W1 = (const float*)d_in[2];
  const float* b1 = (const float*)d_in[3];
  const float* W2 = (const float*)d_in[4];
  const float* b2 = (const float*)d_in[5];
  const float* W3 = (const float*)d_in[6];
  const float* b3 = (const float*)d_in[7];
  float* out = (float*)d_out;

  // 256 blocks x 256 threads = 1024 waves (16 real cols each):
  // 1 wave/SIMD on all 256 CUs — proven-optimal geometry (r6 vs r8/r9).
  node_step_kernel<<<dim3(NB / 64), dim3(256), 0, stream>>>(
      y0, ts, W1, b1, W2, b2, W3, b3, out);
}

// Round 3
// 5456.612 us; speedup vs baseline: 1.2042x; 1.2042x over previous
//
#include <hip/hip_runtime.h>

#define NB 16384
#define NT 1024

typedef _Float16 h8  __attribute__((ext_vector_type(8)));
typedef __fp16   g2  __attribute__((ext_vector_type(2)));   // cvt_pkrtz result type
typedef float    f4  __attribute__((ext_vector_type(4)));

// AS4 scalar loads for wave-uniform data (ts).
typedef __attribute__((address_space(4))) const float cfloat;
static __device__ __forceinline__ const cfloat* as_const(const float* p) {
  return (const cfloat*)(unsigned long long)p;
}

#define TANH_SCALE 2.88539008177792681f  // 2*log2(e), folded into W1/b1/W2/b2

union H8U { h8 v; g2 p[4]; };  // type-pun: 4 packed pairs <-> one MFMA operand

// Pin into VGPR (generous budget required: min_waves=1; r7 proved tight bounds
// re-trigger in-loop rematerialization of the W2 loads -> 34.8 GB FETCH).
#define PINV(x)  asm volatile("" : "+v"(x))

// ---- Round 14 = r11 + quad-batched tanh reciprocal ----
// Ledger from r11/r13 counters: r11 wall 2112 cyc/eval, VALUBusy 1542, but
// countable full-rate VALU only ~430 => the 64 trans ops/eval (32 tanh x
// {v_exp,v_rcp}) cost ~14-17 cyc each ~= half the eval. r13 (LDS table)
// regressed: gather latency unhideable at 1 wave/SIMD. So keep tanh on the
// trans pipe but cut trans count 64 -> 40: one v_rcp serves FOUR tanh via the
// all-but-one-product trick (9 v_mul + 1 v_rcp vs 4 v_rcp). Guard: clamp
// xs <= 31 so the 4-denominator product stays < 2^124 (no inf/NaN leakage;
// tanh at the clamp rounds to 1.0f exactly, matching r11 saturation).
// Also: b2 acc-init hoisted as plain f4 (kills 16 v_mov/eval; value-only, not
// r12's asm-pinned f4), residual pack via fmaf(-1,(float)hi,x) to invite
// v_fma_mix_f32.
__global__ __launch_bounds__(256, 1)
void node_step_kernel(const float* __restrict__ y0,
                      const float* __restrict__ ts,
                      const float* __restrict__ W1,
                      const float* __restrict__ b1,
                      const float* __restrict__ W2,
                      const float* __restrict__ b2,
                      const float* __restrict__ W3,
                      const float* __restrict__ b3,
                      float* __restrict__ out)
{
  const int lane = (int)(threadIdx.x & 63);
  const int wv   = (int)(threadIdx.x >> 6);   // 0..3
  const int col  = lane & 15;                 // batch column within wave
  const int quad = lane >> 4;
  const int gb   = (int)blockIdx.x * 64 + wv * 16 + col;

  // ---- init: W2 A-fragments (x TANH_SCALE), hi/lo f16, as pinned h8 ----
  // A-frag (HW-verified r5/r6): A[m = lane&15][k = quad*8 + j]; k-step adds 32.
  h8 Ah[4][2], Al[4][2];                      // [mtile][kstep]
#pragma unroll
  for (int mt = 0; mt < 4; ++mt) {
    const int m = mt * 16 + col;
#pragma unroll
    for (int ks = 0; ks < 2; ++ks) {
      const float* wp = W2 + m * 64 + ks * 32 + quad * 8;
      H8U hu, lu;
#pragma unroll
      for (int p = 0; p < 4; ++p) {
        const float x0 = wp[2*p]     * TANH_SCALE;
        const float x1 = wp[2*p + 1] * TANH_SCALE;
        const g2 hi = __builtin_amdgcn_cvt_pkrtz(x0, x1);
        hu.p[p] = hi;
        lu.p[p] = __builtin_amdgcn_cvt_pkrtz(x0 - (float)hi.x, x1 - (float)hi.y);
      }
      Ah[mt][ks] = hu.v;  PINV(Ah[mt][ks]);
      Al[mt][ks] = lu.v;  PINV(Al[mt][ks]);
    }
  }

  // b2 (x TANH_SCALE) hoisted as f4: passed directly as MFMA C operand (no
  // per-eval v_movs). W3 rows in C/D layout (col = lane&15,
  // row = mt*16 + quad*4 + reg), pinned as scalars (r11 form).
  f4 accb4[4];
  float w30[4][4], w31[4][4];
#pragma unroll
  for (int mt = 0; mt < 4; ++mt) {
#pragma unroll
    for (int r = 0; r < 4; ++r) {
      const int j2 = mt * 16 + quad * 4 + r;
      accb4[mt][r] = b2[j2] * TANH_SCALE;
      w30[mt][r]  = W3[j2];           PINV(w30[mt][r]);
      w31[mt][r]  = W3[64 + j2];      PINV(w31[mt][r]);
    }
  }

  // L1 weights (x TANH_SCALE) for exactly the 16 rows this lane's B-fragments
  // cover: i<8 -> row = quad*8+i (kstep0); i>=8 -> row = 32+quad*8+(i-8).
  float w1a[16], w1b[16], b1r[16];
#pragma unroll
  for (int i = 0; i < 16; ++i) {
    const int row = (i < 8) ? (quad * 8 + i) : (32 + quad * 8 + (i - 8));
    w1a[i] = W1[2 * row]     * TANH_SCALE;  PINV(w1a[i]);
    w1b[i] = W1[2 * row + 1] * TANH_SCALE;  PINV(w1b[i]);
    b1r[i] = b1[row]         * TANH_SCALE;  PINV(b1r[i]);
  }
  const cfloat* tsc = as_const(ts);
  const float b30 = b3[0], b31 = b3[1];

  float yx = y0[2 * gb], yy = y0[2 * gb + 1];

  float2* __restrict__ outv = (float2*)out;
  if (quad == 0) outv[gb] = make_float2(yx, yy);   // SaveAt includes t0

  const float A21 = (float)(1.0/5.0);
  const float A31 = (float)(3.0/40.0),  A32 = (float)(9.0/40.0);
  const float A41 = (float)(44.0/45.0), A42 = (float)(-56.0/15.0), A43 = (float)(32.0/9.0);
  const float A51 = (float)(19372.0/6561.0), A52 = (float)(-25360.0/2187.0),
              A53 = (float)(64448.0/6561.0), A54 = (float)(-212.0/729.0);
  const float A61 = (float)(9017.0/3168.0), A62 = (float)(-355.0/33.0),
              A63 = (float)(46732.0/5247.0), A64 = (float)(49.0/176.0),
              A65 = (float)(-5103.0/18656.0);
  const float BB1 = (float)(35.0/384.0), BB3 = (float)(500.0/1113.0),
              BB4 = (float)(125.0/192.0), BB5 = (float)(-2187.0/6784.0),
              BB6 = (float)(11.0/84.0);

  float k1x,k1y,k2x,k2y,k3x,k3y,k4x,k4y,k5x,k5y,k6x,k6y;

  // Batched tanh of 4 pre-scaled inputs: 4 exp + 1 rcp (vs 4 exp + 4 rcp).
  // xs clamped to <=31: d = 2^xs+1 <= ~2^31, 4-product <= 2^124 (finite, and
  // rcp of it is still a normal float). tanh(31/2.885) rounds to 1.0f.
  auto TANH4 = [](float x0, float x1, float x2, float x3,
                  float& t0, float& t1, float& t2, float& t3) {
    x0 = __builtin_fminf(x0, 31.0f);
    x1 = __builtin_fminf(x1, 31.0f);
    x2 = __builtin_fminf(x2, 31.0f);
    x3 = __builtin_fminf(x3, 31.0f);
    const float e0 = __builtin_amdgcn_exp2f(x0);
    const float e1 = __builtin_amdgcn_exp2f(x1);
    const float e2 = __builtin_amdgcn_exp2f(x2);
    const float e3 = __builtin_amdgcn_exp2f(x3);
    const float d0 = e0 + 1.0f, d1 = e1 + 1.0f;
    const float d2 = e2 + 1.0f, d3 = e3 + 1.0f;
    const float p01 = d0 * d1, p23 = d2 * d3;
    const float r   = __builtin_amdgcn_rcpf(p01 * p23);
    const float r01 = r * p23, r23 = r * p01;     // 1/(d0 d1), 1/(d2 d3)
    t0 = fmaf(-2.0f, r01 * d1, 1.0f);             // 1 - 2/d0
    t1 = fmaf(-2.0f, r01 * d0, 1.0f);
    t2 = fmaf(-2.0f, r23 * d3, 1.0f);
    t3 = fmaf(-2.0f, r23 * d2, 1.0f);
  };

  for (int t = 0; t < NT - 1; ++t) {
    const float dt = tsc[t + 1] - tsc[t];

    auto EVAL = [&](float ysx, float ysy, float& kx, float& ky) {
      // ---- L1: 16 preacts (2 fma each), then 4 batched tanh quads ----
      float xs[16];
#pragma unroll
      for (int i = 0; i < 16; ++i)
        xs[i] = fmaf(w1a[i], ysx, fmaf(w1b[i], ysy, b1r[i]));
      float hv[16];
#pragma unroll
      for (int g = 0; g < 4; ++g)
        TANH4(xs[4*g], xs[4*g+1], xs[4*g+2], xs[4*g+3],
              hv[4*g], hv[4*g+1], hv[4*g+2], hv[4*g+3]);

      // pair-pack into B-fragments: v_cvt_pkrtz (hi) + residual (fma_mix form)
      H8U BH0, BL0, BH1, BL1;
#pragma unroll
      for (int p = 0; p < 4; ++p) {
        const g2 h0 = __builtin_amdgcn_cvt_pkrtz(hv[2*p], hv[2*p+1]);
        BH0.p[p] = h0;
        BL0.p[p] = __builtin_amdgcn_cvt_pkrtz(
            fmaf(-1.0f, (float)h0.x, hv[2*p]),
            fmaf(-1.0f, (float)h0.y, hv[2*p+1]));
        const g2 h1 = __builtin_amdgcn_cvt_pkrtz(hv[8+2*p], hv[9+2*p]);
        BH1.p[p] = h1;
        BL1.p[p] = __builtin_amdgcn_cvt_pkrtz(
            fmaf(-1.0f, (float)h1.x, hv[8+2*p]),
            fmaf(-1.0f, (float)h1.y, hv[9+2*p]));
      }

      // ---- L2: 4 m-tiles x (2 k-steps x 3 split products) MFMA ----
      float p0 = 0.0f, p1 = 0.0f;
#pragma unroll
      for (int mt = 0; mt < 4; ++mt) {
        f4 c = __builtin_amdgcn_mfma_f32_16x16x32_f16(Al[mt][0], BH0.v, accb4[mt], 0, 0, 0);
        c = __builtin_amdgcn_mfma_f32_16x16x32_f16(Ah[mt][0], BL0.v, c, 0, 0, 0);
        c = __builtin_amdgcn_mfma_f32_16x16x32_f16(Ah[mt][0], BH0.v, c, 0, 0, 0);
        c = __builtin_amdgcn_mfma_f32_16x16x32_f16(Al[mt][1], BH1.v, c, 0, 0, 0);
        c = __builtin_amdgcn_mfma_f32_16x16x32_f16(Ah[mt][1], BL1.v, c, 0, 0, 0);
        c = __builtin_amdgcn_mfma_f32_16x16x32_f16(Ah[mt][1], BH1.v, c, 0, 0, 0);
        // ---- L3 partials: batched tanh on the 4 acc rows + W3 fma ----
        float t0, t1, t2, t3;
        TANH4(c[0], c[1], c[2], c[3], t0, t1, t2, t3);
        p0 = fmaf(w30[mt][0], t0, p0);  p1 = fmaf(w31[mt][0], t0, p1);
        p0 = fmaf(w30[mt][1], t1, p0);  p1 = fmaf(w31[mt][1], t1, p1);
        p0 = fmaf(w30[mt][2], t2, p0);  p1 = fmaf(w31[mt][2], t2, p1);
        p0 = fmaf(w30[mt][3], t3, p0);  p1 = fmaf(w31[mt][3], t3, p1);
      }
      // quad butterfly: lanes col, col^16, col^32, col^48 hold the 4 row-quarters
      p0 += __shfl_xor(p0, 16); p1 += __shfl_xor(p1, 16);
      p0 += __shfl_xor(p0, 32); p1 += __shfl_xor(p1, 32);
      kx = p0 + b30;
      ky = p1 + b31;
    };

    EVAL(yx, yy, k1x, k1y);
    EVAL(fmaf(dt, A21 * k1x, yx), fmaf(dt, A21 * k1y, yy), k2x, k2y);
    {
      float cx = fmaf(A32, k2x, A31 * k1x);
      float cy = fmaf(A32, k2y, A31 * k1y);
      EVAL(fmaf(dt, cx, yx), fmaf(dt, cy, yy), k3x, k3y);
    }
    {
      float cx = fmaf(A43, k3x, fmaf(A42, k2x, A41 * k1x));
      float cy = fmaf(A43, k3y, fmaf(A42, k2y, A41 * k1y));
      EVAL(fmaf(dt, cx, yx), fmaf(dt, cy, yy), k4x, k4y);
    }
    {
      float cx = fmaf(A54, k4x, fmaf(A53, k3x, fmaf(A52, k2x, A51 * k1x)));
      float cy = fmaf(A54, k4y, fmaf(A53, k3y, fmaf(A52, k2y, A51 * k1y)));
      EVAL(fmaf(dt, cx, yx), fmaf(dt, cy, yy), k5x, k5y);
    }
    {
      float cx = fmaf(A65, k5x, fmaf(A64, k4x, fmaf(A63, k3x, fmaf(A62, k2x, A61 * k1x))));
      float cy = fmaf(A65, k5y, fmaf(A64, k4y, fmaf(A63, k3y, fmaf(A62, k2y, A61 * k1y))));
      EVAL(fmaf(dt, cx, yx), fmaf(dt, cy, yy), k6x, k6y);
    }
    {
      float cx = fmaf(BB6, k6x, fmaf(BB5, k5x, fmaf(BB4, k4x, fmaf(BB3, k3x, BB1 * k1x))));
      float cy = fmaf(BB6, k6y, fmaf(BB5, k5y, fmaf(BB4, k4y, fmaf(BB3, k3y, BB1 * k1y))));
      yx = fmaf(dt, cx, yx);
      yy = fmaf(dt, cy, yy);
    }
    if (quad == 0) outv[(t + 1) * NB + gb] = make_float2(yx, yy);
  }
}

extern "C" void kernel_launch(void* const* d_in, const int* in_sizes, int n_in,
                              void* d_out, int out_size, void* d_ws, size_t ws_size,
                              hipStream_t stream) {
  const float* y0 = (const float*)d_in[0];
  const float* ts = (const float*)d_in[1];
  const float* W1 = (const float*)d_in[2];
  const float* b1 = (const float*)d_in[3];
  const float* W2 = (const float*)d_in[4];
  const float* b2 = (const float*)d_in[5];
  const float* W3 = (const float*)d_in[6];
  const float* b3 = (const float*)d_in[7];
  float* out = (float*)d_out;

  // 256 blocks x 256 threads = 1024 waves (16 real cols each):
  // 1 wave/SIMD on all 256 CUs — proven-optimal geometry (r6 vs r8/r9).
  node_step_kernel<<<dim3(NB / 64), dim3(256), 0, stream>>>(
      y0, ts, W1, b1, W2, b2, W3, b3, out);
}

// Round 5
// 4174.147 us; speedup vs baseline: 1.5742x; 1.3072x over previous
//
#include <hip/hip_runtime.h>

#define NB 16384
#define NT 1024

typedef _Float16 h8  __attribute__((ext_vector_type(8)));
typedef __fp16   g2  __attribute__((ext_vector_type(2)));   // cvt_pkrtz result type
typedef float    f4  __attribute__((ext_vector_type(4)));

// AS4 scalar loads for wave-uniform data (ts).
typedef __attribute__((address_space(4))) const float cfloat;
static __device__ __forceinline__ const cfloat* as_const(const float* p) {
  return (const cfloat*)(unsigned long long)p;
}

// Pre-scaled tanh: input already multiplied by 2*log2(e) (folded into weights).
// tanh(x) = 1 - 2/(exp2(xs)+1), xs = 2*log2(e)*x. 4 inst: exp, add, rcp, fma.
// Saturation is free: xs->+inf => rcp(inf)=0 => 1; xs->-inf => 1-2 = -1.
static __device__ __forceinline__ float tanh_ps(float xs) {
  float e = __builtin_amdgcn_exp2f(xs);
  return fmaf(-2.0f, __builtin_amdgcn_rcpf(e + 1.0f), 1.0f);
}

#define TANH_SCALE 2.88539008177792681f  // 2*log2(e)

union H8U { h8 v; g2 p[4]; };  // type-pun: 4 packed pairs <-> one MFMA operand

// Pin into VGPR (generous budget required: min_waves=1; r7 proved tight bounds
// re-trigger in-loop rematerialization of the W2 loads -> 34.8 GB FETCH).
#define PINV(x)  asm volatile("" : "+v"(x))

// ---- Round 15 (resubmit; round-4 run died in the container broker) ----
// = r11 minus the B-fragment lo-split.
// r13 (LDS table) and r14 (batched rcp) both REGRESSED => trans ops are cheap
// (~4-8 cyc, quarter-rate) and r11's 4-inst tanh is near-optimal; the VALU
// ledger at a throttled ~1.6GHz effective clock is ~fully issue-bound with no
// tanh fat. Remaining per-eval fat: the B hi/lo split = 40 full-rate inst
// (16 cvt + 16 sub + 8 pkrtz) + 8 MFMAs + 2 extra deps per mt chain.
// Precision: h1 in (-1,1) at plain f16 -> <=2.4e-4 elem err -> h2 ~1e-4 ->
// k ~1e-4 -> steady-state ~1e-3 under contracting dynamics; threshold 0.08,
// r11 scored 0.0078 (1 bf16 ulp). A-side split kept (zero per-eval cost).
__global__ __launch_bounds__(256, 1)
void node_step_kernel(const float* __restrict__ y0,
                      const float* __restrict__ ts,
                      const float* __restrict__ W1,
                      const float* __restrict__ b1,
                      const float* __restrict__ W2,
                      const float* __restrict__ b2,
                      const float* __restrict__ W3,
                      const float* __restrict__ b3,
                      float* __restrict__ out)
{
  const int lane = (int)(threadIdx.x & 63);
  const int wv   = (int)(threadIdx.x >> 6);   // 0..3
  const int col  = lane & 15;                 // batch column within wave
  const int quad = lane >> 4;
  const int gb   = (int)blockIdx.x * 64 + wv * 16 + col;

  // ---- init: W2 A-fragments (x TANH_SCALE), hi/lo f16, as pinned h8 ----
  // A-frag (HW-verified r5/r6): A[m = lane&15][k = quad*8 + j]; k-step adds 32.
  h8 Ah[4][2], Al[4][2];                      // [mtile][kstep]
#pragma unroll
  for (int mt = 0; mt < 4; ++mt) {
    const int m = mt * 16 + col;
#pragma unroll
    for (int ks = 0; ks < 2; ++ks) {
      const float* wp = W2 + m * 64 + ks * 32 + quad * 8;
      H8U hu, lu;
#pragma unroll
      for (int p = 0; p < 4; ++p) {
        const float x0 = wp[2*p]     * TANH_SCALE;
        const float x1 = wp[2*p + 1] * TANH_SCALE;
        const g2 hi = __builtin_amdgcn_cvt_pkrtz(x0, x1);
        hu.p[p] = hi;
        lu.p[p] = __builtin_amdgcn_cvt_pkrtz(x0 - (float)hi.x, x1 - (float)hi.y);
      }
      Ah[mt][ks] = hu.v;  PINV(Ah[mt][ks]);
      Al[mt][ks] = lu.v;  PINV(Al[mt][ks]);
    }
  }

  // b2 (x TANH_SCALE, acc init) and W3 rows in C/D layout (HW-verified:
  // col = lane&15, row = mt*16 + quad*4 + reg). Pinned. (r11 verbatim form.)
  float accb[4][4], w30[4][4], w31[4][4];
#pragma unroll
  for (int mt = 0; mt < 4; ++mt) {
#pragma unroll
    for (int r = 0; r < 4; ++r) {
      const int j2 = mt * 16 + quad * 4 + r;
      accb[mt][r] = b2[j2] * TANH_SCALE;  PINV(accb[mt][r]);
      w30[mt][r]  = W3[j2];               PINV(w30[mt][r]);
      w31[mt][r]  = W3[64 + j2];          PINV(w31[mt][r]);
    }
  }

  // L1 weights (x TANH_SCALE) for exactly the 16 rows this lane's B-fragments
  // cover: i<8 -> row = quad*8+i (kstep0); i>=8 -> row = 32+quad*8+(i-8).
  float w1a[16], w1b[16], b1r[16];
#pragma unroll
  for (int i = 0; i < 16; ++i) {
    const int row = (i < 8) ? (quad * 8 + i) : (32 + quad * 8 + (i - 8));
    w1a[i] = W1[2 * row]     * TANH_SCALE;  PINV(w1a[i]);
    w1b[i] = W1[2 * row + 1] * TANH_SCALE;  PINV(w1b[i]);
    b1r[i] = b1[row]         * TANH_SCALE;  PINV(b1r[i]);
  }
  const cfloat* tsc = as_const(ts);
  const float b30 = b3[0], b31 = b3[1];

  float yx = y0[2 * gb], yy = y0[2 * gb + 1];

  float2* __restrict__ outv = (float2*)out;
  if (quad == 0) outv[gb] = make_float2(yx, yy);   // SaveAt includes t0

  const float A21 = (float)(1.0/5.0);
  const float A31 = (float)(3.0/40.0),  A32 = (float)(9.0/40.0);
  const float A41 = (float)(44.0/45.0), A42 = (float)(-56.0/15.0), A43 = (float)(32.0/9.0);
  const float A51 = (float)(19372.0/6561.0), A52 = (float)(-25360.0/2187.0),
              A53 = (float)(64448.0/6561.0), A54 = (float)(-212.0/729.0);
  const float A61 = (float)(9017.0/3168.0), A62 = (float)(-355.0/33.0),
              A63 = (float)(46732.0/5247.0), A64 = (float)(49.0/176.0),
              A65 = (float)(-5103.0/18656.0);
  const float BB1 = (float)(35.0/384.0), BB3 = (float)(500.0/1113.0),
              BB4 = (float)(125.0/192.0), BB5 = (float)(-2187.0/6784.0),
              BB6 = (float)(11.0/84.0);

  float k1x,k1y,k2x,k2y,k3x,k3y,k4x,k4y,k5x,k5y,k6x,k6y;

  for (int t = 0; t < NT - 1; ++t) {
    const float dt = tsc[t + 1] - tsc[t];

    auto EVAL = [&](float ysx, float ysy, float& kx, float& ky) {
      // ---- L1: 16 h1 rows (pre-scaled weights -> 2 fma + 4-inst tanh) ----
      float hv[16];
#pragma unroll
      for (int i = 0; i < 16; ++i)
        hv[i] = tanh_ps(fmaf(w1a[i], ysx, fmaf(w1b[i], ysy, b1r[i])));

      // pair-pack into B-fragments via v_cvt_pkrtz — HI ONLY (lo dropped:
      // h1 at plain f16 costs <=2.4e-4/elem, ~1e-3 end-to-end; thr 0.08)
      H8U BH0, BH1;
#pragma unroll
      for (int p = 0; p < 4; ++p) {
        BH0.p[p] = __builtin_amdgcn_cvt_pkrtz(hv[2*p],   hv[2*p+1]);
        BH1.p[p] = __builtin_amdgcn_cvt_pkrtz(hv[8+2*p], hv[9+2*p]);
      }

      // ---- L2: 4 m-tiles x (2 k-steps x 2 A-split products) MFMA ----
      float p0 = 0.0f, p1 = 0.0f;
#pragma unroll
      for (int mt = 0; mt < 4; ++mt) {
        f4 c = { accb[mt][0], accb[mt][1], accb[mt][2], accb[mt][3] };
        c = __builtin_amdgcn_mfma_f32_16x16x32_f16(Al[mt][0], BH0.v, c, 0, 0, 0);
        c = __builtin_amdgcn_mfma_f32_16x16x32_f16(Ah[mt][0], BH0.v, c, 0, 0, 0);
        c = __builtin_amdgcn_mfma_f32_16x16x32_f16(Al[mt][1], BH1.v, c, 0, 0, 0);
        c = __builtin_amdgcn_mfma_f32_16x16x32_f16(Ah[mt][1], BH1.v, c, 0, 0, 0);
        // ---- L3 partials: tanh (pre-scale folded into W2/b2) + W3 ----
#pragma unroll
        for (int r = 0; r < 4; ++r) {
          const float h2 = tanh_ps(c[r]);
          p0 = fmaf(w30[mt][r], h2, p0);
          p1 = fmaf(w31[mt][r], h2, p1);
        }
      }
      // quad butterfly: lanes col, col^16, col^32, col^48 hold the 4 row-quarters
      p0 += __shfl_xor(p0, 16); p1 += __shfl_xor(p1, 16);
      p0 += __shfl_xor(p0, 32); p1 += __shfl_xor(p1, 32);
      kx = p0 + b30;
      ky = p1 + b31;
    };

    EVAL(yx, yy, k1x, k1y);
    EVAL(fmaf(dt, A21 * k1x, yx), fmaf(dt, A21 * k1y, yy), k2x, k2y);
    {
      float cx = fmaf(A32, k2x, A31 * k1x);
      float cy = fmaf(A32, k2y, A31 * k1y);
      EVAL(fmaf(dt, cx, yx), fmaf(dt, cy, yy), k3x, k3y);
    }
    {
      float cx = fmaf(A43, k3x, fmaf(A42, k2x, A41 * k1x));
      float cy = fmaf(A43, k3y, fmaf(A42, k2y, A41 * k1y));
      EVAL(fmaf(dt, cx, yx), fmaf(dt, cy, yy), k4x, k4y);
    }
    {
      float cx = fmaf(A54, k4x, fmaf(A53, k3x, fmaf(A52, k2x, A51 * k1x)));
      float cy = fmaf(A54, k4y, fmaf(A53, k3y, fmaf(A52, k2y, A51 * k1y)));
      EVAL(fmaf(dt, cx, yx), fmaf(dt, cy, yy), k5x, k5y);
    }
    {
      float cx = fmaf(A65, k5x, fmaf(A64, k4x, fmaf(A63, k3x, fmaf(A62, k2x, A61 * k1x))));
      float cy = fmaf(A65, k5y, fmaf(A64, k4y, fmaf(A63, k3y, fmaf(A62, k2y, A61 * k1y))));
      EVAL(fmaf(dt, cx, yx), fmaf(dt, cy, yy), k6x, k6y);
    }
    {
      float cx = fmaf(BB6, k6x, fmaf(BB5, k5x, fmaf(BB4, k4x, fmaf(BB3, k3x, BB1 * k1x))));
      float cy = fmaf(BB6, k6y, fmaf(BB5, k5y, fmaf(BB4, k4y, fmaf(BB3, k3y, BB1 * k1y))));
      yx = fmaf(dt, cx, yx);
      yy = fmaf(dt, cy, yy);
    }
    if (quad == 0) outv[(t + 1) * NB + gb] = make_float2(yx, yy);
  }
}

extern "C" void kernel_launch(void* const* d_in, const int* in_sizes, int n_in,
                              void* d_out, int out_size, void* d_ws, size_t ws_size,
                              hipStream_t stream) {
  const float* y0 = (const float*)d_in[0];
  const float* ts = (const float*)d_in[1];
  const float* W1 = (const float*)d_in[2];
  const float* b1 = (const float*)d_in[3];
  const float* W2 = (const float*)d_in[4];
  const float* b2 = (const float*)d_in[5];
  const float* W3 = (const float*)d_in[6];
  const float* b3 = (const float*)d_in[7];
  float* out = (float*)d_out;

  // 256 blocks x 256 threads = 1024 waves (16 real cols each):
  // 1 wave/SIMD on all 256 CUs — proven-optimal geometry (r6 vs r8/r9).
  node_step_kernel<<<dim3(NB / 64), dim3(256), 0, stream>>>(
      y0, ts, W1, b1, W2, b2, W3, b3, out);
}

// Round 7
// 3935.216 us; speedup vs baseline: 1.6698x; 1.0607x over previous
//
#include <hip/hip_runtime.h>

#define NB 16384
#define NT 1024

typedef _Float16 h8  __attribute__((ext_vector_type(8)));
typedef __fp16   g2  __attribute__((ext_vector_type(2)));   // cvt_pkrtz result type
typedef float    f4  __attribute__((ext_vector_type(4)));
typedef float    f2  __attribute__((ext_vector_type(2)));   // v_pk_*_f32 operand

// AS4 scalar loads for wave-uniform data (ts).
typedef __attribute__((address_space(4))) const float cfloat;
static __device__ __forceinline__ const cfloat* as_const(const float* p) {
  return (const cfloat*)(unsigned long long)p;
}

#define TANH_SCALE 2.88539008177792681f  // 2*log2(e)

// Packed fma on f2 -> v_pk_fma_f32 (gfx950 has packed FP32 VOP3P).
// Function (not macro): r16's macro died on braced init-list commas.
static __device__ __forceinline__ f2 pkfma(f2 a, f2 b, f2 c) {
#if __has_builtin(__builtin_elementwise_fma)
  return __builtin_elementwise_fma(a, b, c);
#else
  return a * b + c;   // pk_mul + pk_add fallback
#endif
}

// Packed pre-scaled tanh of a pair: 2 v_exp + 1 pk_add + 2 v_rcp + 1 pk_fma
// (vs 8 scalar inst for two tanh). Saturation free: +inf -> 1, -inf -> -1.
static __device__ __forceinline__ f2 tanh2(f2 xs) {
  const float e0 = __builtin_amdgcn_exp2f(xs.x);
  const float e1 = __builtin_amdgcn_exp2f(xs.y);
  const f2 d = f2{e0, e1} + 1.0f;                       // v_pk_add_f32
  const f2 r = { __builtin_amdgcn_rcpf(d.x), __builtin_amdgcn_rcpf(d.y) };
  return pkfma(f2{-2.0f, -2.0f}, r, f2{1.0f, 1.0f});    // v_pk_fma_f32
}

union H8U { h8 v; g2 p[4]; };  // type-pun: 4 packed pairs <-> one MFMA operand

// Pin into VGPR (generous budget required: min_waves=1; r7 proved tight bounds
// re-trigger in-loop rematerialization of the W2 loads -> 34.8 GB FETCH).
#define PINV(x)  asm volatile("" : "+v"(x))

// ---- Round 16 (resubmit, macro->function fix) = r15 + packed-f32 VOP3P ----
// r15 confirmed the kernel is VALU-ISSUE-bound (VALUBusy 73 + MfmaUtil 16
// ~= 89%; r8/r9: 2 waves/SIMD = 2x time). Ledger ~1050 cyc/eval. This round
// packs all pairable scalar-f32 math into v_pk_* (bit-exact vs scalar fma):
// preacts (w1 as f2 pairs), tanh's add/fma (trans stays scalar), L3 accum
// (p0/p1 as f2 over r-pairs + one horizontal add). Predicted -58 inst/eval
// ~= -11% wall. Precision untouched by construction.
__global__ __launch_bounds__(256, 1)
void node_step_kernel(const float* __restrict__ y0,
                      const float* __restrict__ ts,
                      const float* __restrict__ W1,
                      const float* __restrict__ b1,
                      const float* __restrict__ W2,
                      const float* __restrict__ b2,
                      const float* __restrict__ W3,
                      const float* __restrict__ b3,
                      float* __restrict__ out)
{
  const int lane = (int)(threadIdx.x & 63);
  const int wv   = (int)(threadIdx.x >> 6);   // 0..3
  const int col  = lane & 15;                 // batch column within wave
  const int quad = lane >> 4;
  const int gb   = (int)blockIdx.x * 64 + wv * 16 + col;

  // ---- init: W2 A-fragments (x TANH_SCALE), hi/lo f16, as pinned h8 ----
  // A-frag (HW-verified r5/r6): A[m = lane&15][k = quad*8 + j]; k-step adds 32.
  h8 Ah[4][2], Al[4][2];                      // [mtile][kstep]
#pragma unroll
  for (int mt = 0; mt < 4; ++mt) {
    const int m = mt * 16 + col;
#pragma unroll
    for (int ks = 0; ks < 2; ++ks) {
      const float* wp = W2 + m * 64 + ks * 32 + quad * 8;
      H8U hu, lu;
#pragma unroll
      for (int p = 0; p < 4; ++p) {
        const float x0 = wp[2*p]     * TANH_SCALE;
        const float x1 = wp[2*p + 1] * TANH_SCALE;
        const g2 hi = __builtin_amdgcn_cvt_pkrtz(x0, x1);
        hu.p[p] = hi;
        lu.p[p] = __builtin_amdgcn_cvt_pkrtz(x0 - (float)hi.x, x1 - (float)hi.y);
      }
      Ah[mt][ks] = hu.v;  PINV(Ah[mt][ks]);
      Al[mt][ks] = lu.v;  PINV(Al[mt][ks]);
    }
  }

  // b2 (x TANH_SCALE, acc init) scalar+pinned (r15 form). W3 rows in C/D
  // layout (col = lane&15, row = mt*16 + quad*4 + r), pair-grouped for the
  // packed L3 accumulation: a = rows (r0,r1), b = rows (r2,r3).
  float accb[4][4];
  f2 w30a[4], w30b[4], w31a[4], w31b[4];
#pragma unroll
  for (int mt = 0; mt < 4; ++mt) {
#pragma unroll
    for (int r = 0; r < 4; ++r) {
      accb[mt][r] = b2[mt * 16 + quad * 4 + r] * TANH_SCALE;  PINV(accb[mt][r]);
    }
    const int j2 = mt * 16 + quad * 4;
    w30a[mt] = f2{W3[j2 + 0],      W3[j2 + 1]};       PINV(w30a[mt]);
    w30b[mt] = f2{W3[j2 + 2],      W3[j2 + 3]};       PINV(w30b[mt]);
    w31a[mt] = f2{W3[64 + j2 + 0], W3[64 + j2 + 1]};  PINV(w31a[mt]);
    w31b[mt] = f2{W3[64 + j2 + 2], W3[64 + j2 + 3]};  PINV(w31b[mt]);
  }

  // L1 weights (x TANH_SCALE) as f2 pairs; pair p covers B-fragment elements
  // (2p, 2p+1): p<4 -> rows quad*8+{2p,2p+1} (kstep0); p>=4 -> rows
  // 32+quad*8+{2p-8,2p-7} (kstep1). Pairs never straddle the kstep boundary.
  f2 w1a2[8], w1b2[8], b1r2[8];
#pragma unroll
  for (int p = 0; p < 8; ++p) {
    const int e0 = 2 * p;
    const int row0 = (e0 < 8) ? (quad * 8 + e0) : (32 + quad * 8 + (e0 - 8));
    const int row1 = row0 + 1;
    w1a2[p] = f2{W1[2 * row0],     W1[2 * row1]}     * TANH_SCALE;  PINV(w1a2[p]);
    w1b2[p] = f2{W1[2 * row0 + 1], W1[2 * row1 + 1]} * TANH_SCALE;  PINV(w1b2[p]);
    b1r2[p] = f2{b1[row0],         b1[row1]}         * TANH_SCALE;  PINV(b1r2[p]);
  }
  const cfloat* tsc = as_const(ts);
  const float b30 = b3[0], b31 = b3[1];

  float yx = y0[2 * gb], yy = y0[2 * gb + 1];

  float2* __restrict__ outv = (float2*)out;
  if (quad == 0) outv[gb] = make_float2(yx, yy);   // SaveAt includes t0

  const float A21 = (float)(1.0/5.0);
  const float A31 = (float)(3.0/40.0),  A32 = (float)(9.0/40.0);
  const float A41 = (float)(44.0/45.0), A42 = (float)(-56.0/15.0), A43 = (float)(32.0/9.0);
  const float A51 = (float)(19372.0/6561.0), A52 = (float)(-25360.0/2187.0),
              A53 = (float)(64448.0/6561.0), A54 = (float)(-212.0/729.0);
  const float A61 = (float)(9017.0/3168.0), A62 = (float)(-355.0/33.0),
              A63 = (float)(46732.0/5247.0), A64 = (float)(49.0/176.0),
              A65 = (float)(-5103.0/18656.0);
  const float BB1 = (float)(35.0/384.0), BB3 = (float)(500.0/1113.0),
              BB4 = (float)(125.0/192.0), BB5 = (float)(-2187.0/6784.0),
              BB6 = (float)(11.0/84.0);

  float k1x,k1y,k2x,k2y,k3x,k3y,k4x,k4y,k5x,k5y,k6x,k6y;

  for (int t = 0; t < NT - 1; ++t) {
    const float dt = tsc[t + 1] - tsc[t];

    auto EVAL = [&](float ysx, float ysy, float& kx, float& ky) {
      // ---- L1: 8 preact pairs (2 pk_fma each) + 8 packed tanh pairs ----
      const f2 ysx2 = {ysx, ysx}, ysy2 = {ysy, ysy};
      f2 hv2[8];
#pragma unroll
      for (int p = 0; p < 8; ++p)
        hv2[p] = tanh2(pkfma(w1a2[p], ysx2, pkfma(w1b2[p], ysy2, b1r2[p])));

      // pair-pack into B-fragments via v_cvt_pkrtz — HI ONLY (r15: lo dropped;
      // h1 at plain f16 ~1e-3 end-to-end, thr 0.08). hv2 pairs == pkrtz pairs.
      H8U BH0, BH1;
#pragma unroll
      for (int p = 0; p < 4; ++p) {
        BH0.p[p] = __builtin_amdgcn_cvt_pkrtz(hv2[p].x,     hv2[p].y);
        BH1.p[p] = __builtin_amdgcn_cvt_pkrtz(hv2[4 + p].x, hv2[4 + p].y);
      }

      // ---- L2: 4 m-tiles x (2 k-steps x 2 A-split products) MFMA ----
      // ---- L3: packed tanh on acc pairs + packed W3 accumulation ----
      f2 pa = {0.0f, 0.0f}, pb = {0.0f, 0.0f};   // pa: p0 over r-pairs; pb: p1
#pragma unroll
      for (int mt = 0; mt < 4; ++mt) {
        f4 c = { accb[mt][0], accb[mt][1], accb[mt][2], accb[mt][3] };
        c = __builtin_amdgcn_mfma_f32_16x16x32_f16(Al[mt][0], BH0.v, c, 0, 0, 0);
        c = __builtin_amdgcn_mfma_f32_16x16x32_f16(Ah[mt][0], BH0.v, c, 0, 0, 0);
        c = __builtin_amdgcn_mfma_f32_16x16x32_f16(Al[mt][1], BH1.v, c, 0, 0, 0);
        c = __builtin_amdgcn_mfma_f32_16x16x32_f16(Ah[mt][1], BH1.v, c, 0, 0, 0);
        const f2 t01 = tanh2(f2{c[0], c[1]});
        const f2 t23 = tanh2(f2{c[2], c[3]});
        pa = pkfma(w30a[mt], t01, pa);
        pa = pkfma(w30b[mt], t23, pa);
        pb = pkfma(w31a[mt], t01, pb);
        pb = pkfma(w31b[mt], t23, pb);
      }
      float p0 = pa.x + pa.y;
      float p1 = pb.x + pb.y;
      // quad butterfly: lanes col, col^16, col^32, col^48 hold the 4 row-quarters
      p0 += __shfl_xor(p0, 16); p1 += __shfl_xor(p1, 16);
      p0 += __shfl_xor(p0, 32); p1 += __shfl_xor(p1, 32);
      kx = p0 + b30;
      ky = p1 + b31;
    };

    EVAL(yx, yy, k1x, k1y);
    EVAL(fmaf(dt, A21 * k1x, yx), fmaf(dt, A21 * k1y, yy), k2x, k2y);
    {
      float cx = fmaf(A32, k2x, A31 * k1x);
      float cy = fmaf(A32, k2y, A31 * k1y);
      EVAL(fmaf(dt, cx, yx), fmaf(dt, cy, yy), k3x, k3y);
    }
    {
      float cx = fmaf(A43, k3x, fmaf(A42, k2x, A41 * k1x));
      float cy = fmaf(A43, k3y, fmaf(A42, k2y, A41 * k1y));
      EVAL(fmaf(dt, cx, yx), fmaf(dt, cy, yy), k4x, k4y);
    }
    {
      float cx = fmaf(A54, k4x, fmaf(A53, k3x, fmaf(A52, k2x, A51 * k1x)));
      float cy = fmaf(A54, k4y, fmaf(A53, k3y, fmaf(A52, k2y, A51 * k1y)));
      EVAL(fmaf(dt, cx, yx), fmaf(dt, cy, yy), k5x, k5y);
    }
    {
      float cx = fmaf(A65, k5x, fmaf(A64, k4x, fmaf(A63, k3x, fmaf(A62, k2x, A61 * k1x))));
      float cy = fmaf(A65, k5y, fmaf(A64, k4y, fmaf(A63, k3y, fmaf(A62, k2y, A61 * k1y))));
      EVAL(fmaf(dt, cx, yx), fmaf(dt, cy, yy), k6x, k6y);
    }
    {
      float cx = fmaf(BB6, k6x, fmaf(BB5, k5x, fmaf(BB4, k4x, fmaf(BB3, k3x, BB1 * k1x))));
      float cy = fmaf(BB6, k6y, fmaf(BB5, k5y, fmaf(BB4, k4y, fmaf(BB3, k3y, BB1 * k1y))));
      yx = fmaf(dt, cx, yx);
      yy = fmaf(dt, cy, yy);
    }
    if (quad == 0) outv[(t + 1) * NB + gb] = make_float2(yx, yy);
  }
}

extern "C" void kernel_launch(void* const* d_in, const int* in_sizes, int n_in,
                              void* d_out, int out_size, void* d_ws, size_t ws_size,
                              hipStream_t stream) {
  const float* y0 = (const float*)d_in[0];
  const float* ts = (const float*)d_in[1];
  const float* W1 = (const float*)d_in[2];
  const float* b1 = (const float*)d_in[3];
  const float* W2 = (const float*)d_in[4];
  const float* b2 = (const float*)d_in[5];
  const float* W3 = (const float*)d_in[6];
  const float* b3 = (const float*)d_in[7];
  float* out = (float*)d_out;

  // 256 blocks x 256 threads = 1024 waves (16 real cols each):
  // 1 wave/SIMD on all 256 CUs — proven-optimal geometry (r6 vs r8/r9).
  node_step_kernel<<<dim3(NB / 64), dim3(256), 0, stream>>>(
      y0, ts, W1, b1, W2, b2, W3, b3, out);
}

// Round 8
// 3528.373 us; speedup vs baseline: 1.8623x; 1.1153x over previous
//
#include <hip/hip_runtime.h>

#define NB 16384
#define NT 1024

typedef _Float16 h8  __attribute__((ext_vector_type(8)));
typedef __fp16   g2  __attribute__((ext_vector_type(2)));   // cvt_pkrtz result type
typedef float    f4  __attribute__((ext_vector_type(4)));
typedef float    f2  __attribute__((ext_vector_type(2)));   // v_pk_*_f32 operand

// AS4 scalar loads for wave-uniform data (ts).
typedef __attribute__((address_space(4))) const float cfloat;
static __device__ __forceinline__ const cfloat* as_const(const float* p) {
  return (const cfloat*)(unsigned long long)p;
}

#define TANH_SCALE 2.88539008177792681f  // 2*log2(e)

// Packed fma on f2 -> v_pk_fma_f32 (gfx950 packed FP32 VOP3P).
static __device__ __forceinline__ f2 pkfma(f2 a, f2 b, f2 c) {
#if __has_builtin(__builtin_elementwise_fma)
  return __builtin_elementwise_fma(a, b, c);
#else
  return a * b + c;   // pk_mul + pk_add fallback
#endif
}

// Packed pre-scaled tanh of a pair: 2 v_exp + 1 pk_add + 2 v_rcp + 1 pk_fma.
// Saturation free: +inf -> 1, -inf -> -1.
static __device__ __forceinline__ f2 tanh2(f2 xs) {
  const float e0 = __builtin_amdgcn_exp2f(xs.x);
  const float e1 = __builtin_amdgcn_exp2f(xs.y);
  const f2 d = f2{e0, e1} + 1.0f;                       // v_pk_add_f32
  const f2 r = { __builtin_amdgcn_rcpf(d.x), __builtin_amdgcn_rcpf(d.y) };
  return pkfma(f2{-2.0f, -2.0f}, r, f2{1.0f, 1.0f});    // v_pk_fma_f32
}

union H8U { h8 v; g2 p[4]; };  // type-pun: 4 packed pairs <-> one MFMA operand

// Pin into VGPR (generous budget required: min_waves=1; r7 proved tight bounds
// re-trigger in-loop rematerialization of the W2 loads -> 34.8 GB FETCH).
#define PINV(x)  asm volatile("" : "+v"(x))

// ---- Round 17 = r16 minus the A-side (W2) lo-split ----
// r16 counters: VALUBusy 65.6 + MfmaUtil 16.6 = 82% => ~18% stall tail at
// 1 wave/SIMD; trans floor ~512 cyc of 790 busy (untouchable, r13/r14).
// This round is the symmetric twin of r15's proven B-drop: W2 at plain f16
// (rel err 4.9e-4, same order as the B-drop that cost 1 bf16 ulp). Halves
// MFMA count 16 -> 8 AND shortens each mt's serial chain 4 -> 2 (stall tail).
// Pure deletion; fallback if absmax > 0.08 is revert + permlane butterfly.
__global__ __launch_bounds__(256, 1)
void node_step_kernel(const float* __restrict__ y0,
                      const float* __restrict__ ts,
                      const float* __restrict__ W1,
                      const float* __restrict__ b1,
                      const float* __restrict__ W2,
                      const float* __restrict__ b2,
                      const float* __restrict__ W3,
                      const float* __restrict__ b3,
                      float* __restrict__ out)
{
  const int lane = (int)(threadIdx.x & 63);
  const int wv   = (int)(threadIdx.x >> 6);   // 0..3
  const int col  = lane & 15;                 // batch column within wave
  const int quad = lane >> 4;
  const int gb   = (int)blockIdx.x * 64 + wv * 16 + col;

  // ---- init: W2 A-fragments (x TANH_SCALE), plain f16 (hi only), pinned ----
  // A-frag (HW-verified r5/r6): A[m = lane&15][k = quad*8 + j]; k-step adds 32.
  h8 Ah[4][2];                                // [mtile][kstep]
#pragma unroll
  for (int mt = 0; mt < 4; ++mt) {
    const int m = mt * 16 + col;
#pragma unroll
    for (int ks = 0; ks < 2; ++ks) {
      const float* wp = W2 + m * 64 + ks * 32 + quad * 8;
      H8U hu;
#pragma unroll
      for (int p = 0; p < 4; ++p)
        hu.p[p] = __builtin_amdgcn_cvt_pkrtz(wp[2*p]     * TANH_SCALE,
                                             wp[2*p + 1] * TANH_SCALE);
      Ah[mt][ks] = hu.v;  PINV(Ah[mt][ks]);
    }
  }

  // b2 (x TANH_SCALE, acc init) scalar+pinned. W3 rows in C/D layout
  // (col = lane&15, row = mt*16 + quad*4 + r), pair-grouped for packed L3.
  float accb[4][4];
  f2 w30a[4], w30b[4], w31a[4], w31b[4];
#pragma unroll
  for (int mt = 0; mt < 4; ++mt) {
#pragma unroll
    for (int r = 0; r < 4; ++r) {
      accb[mt][r] = b2[mt * 16 + quad * 4 + r] * TANH_SCALE;  PINV(accb[mt][r]);
    }
    const int j2 = mt * 16 + quad * 4;
    w30a[mt] = f2{W3[j2 + 0],      W3[j2 + 1]};       PINV(w30a[mt]);
    w30b[mt] = f2{W3[j2 + 2],      W3[j2 + 3]};       PINV(w30b[mt]);
    w31a[mt] = f2{W3[64 + j2 + 0], W3[64 + j2 + 1]};  PINV(w31a[mt]);
    w31b[mt] = f2{W3[64 + j2 + 2], W3[64 + j2 + 3]};  PINV(w31b[mt]);
  }

  // L1 weights (x TANH_SCALE) as f2 pairs; pair p covers B-fragment elements
  // (2p, 2p+1): p<4 -> rows quad*8+{2p,2p+1} (kstep0); p>=4 -> rows
  // 32+quad*8+{2p-8,2p-7} (kstep1). Pairs never straddle the kstep boundary.
  f2 w1a2[8], w1b2[8], b1r2[8];
#pragma unroll
  for (int p = 0; p < 8; ++p) {
    const int e0 = 2 * p;
    const int row0 = (e0 < 8) ? (quad * 8 + e0) : (32 + quad * 8 + (e0 - 8));
    const int row1 = row0 + 1;
    w1a2[p] = f2{W1[2 * row0],     W1[2 * row1]}     * TANH_SCALE;  PINV(w1a2[p]);
    w1b2[p] = f2{W1[2 * row0 + 1], W1[2 * row1 + 1]} * TANH_SCALE;  PINV(w1b2[p]);
    b1r2[p] = f2{b1[row0],         b1[row1]}         * TANH_SCALE;  PINV(b1r2[p]);
  }
  const cfloat* tsc = as_const(ts);
  const float b30 = b3[0], b31 = b3[1];

  float yx = y0[2 * gb], yy = y0[2 * gb + 1];

  float2* __restrict__ outv = (float2*)out;
  if (quad == 0) outv[gb] = make_float2(yx, yy);   // SaveAt includes t0

  const float A21 = (float)(1.0/5.0);
  const float A31 = (float)(3.0/40.0),  A32 = (float)(9.0/40.0);
  const float A41 = (float)(44.0/45.0), A42 = (float)(-56.0/15.0), A43 = (float)(32.0/9.0);
  const float A51 = (float)(19372.0/6561.0), A52 = (float)(-25360.0/2187.0),
              A53 = (float)(64448.0/6561.0), A54 = (float)(-212.0/729.0);
  const float A61 = (float)(9017.0/3168.0), A62 = (float)(-355.0/33.0),
              A63 = (float)(46732.0/5247.0), A64 = (float)(49.0/176.0),
              A65 = (float)(-5103.0/18656.0);
  const float BB1 = (float)(35.0/384.0), BB3 = (float)(500.0/1113.0),
              BB4 = (float)(125.0/192.0), BB5 = (float)(-2187.0/6784.0),
              BB6 = (float)(11.0/84.0);

  float k1x,k1y,k2x,k2y,k3x,k3y,k4x,k4y,k5x,k5y,k6x,k6y;

  for (int t = 0; t < NT - 1; ++t) {
    const float dt = tsc[t + 1] - tsc[t];

    auto EVAL = [&](float ysx, float ysy, float& kx, float& ky) {
      // ---- L1: 8 preact pairs (2 pk_fma each) + 8 packed tanh pairs ----
      const f2 ysx2 = {ysx, ysx}, ysy2 = {ysy, ysy};
      f2 hv2[8];
#pragma unroll
      for (int p = 0; p < 8; ++p)
        hv2[p] = tanh2(pkfma(w1a2[p], ysx2, pkfma(w1b2[p], ysy2, b1r2[p])));

      // pair-pack into B-fragments via v_cvt_pkrtz (hi only, r15-proven)
      H8U BH0, BH1;
#pragma unroll
      for (int p = 0; p < 4; ++p) {
        BH0.p[p] = __builtin_amdgcn_cvt_pkrtz(hv2[p].x,     hv2[p].y);
        BH1.p[p] = __builtin_amdgcn_cvt_pkrtz(hv2[4 + p].x, hv2[4 + p].y);
      }

      // ---- L2: 4 m-tiles x 2 k-steps, single f16 product (A-lo dropped) ----
      // ---- L3: packed tanh on acc pairs + packed W3 accumulation ----
      f2 pa = {0.0f, 0.0f}, pb = {0.0f, 0.0f};   // pa: p0 over r-pairs; pb: p1
#pragma unroll
      for (int mt = 0; mt < 4; ++mt) {
        f4 c = { accb[mt][0], accb[mt][1], accb[mt][2], accb[mt][3] };
        c = __builtin_amdgcn_mfma_f32_16x16x32_f16(Ah[mt][0], BH0.v, c, 0, 0, 0);
        c = __builtin_amdgcn_mfma_f32_16x16x32_f16(Ah[mt][1], BH1.v, c, 0, 0, 0);
        const f2 t01 = tanh2(f2{c[0], c[1]});
        const f2 t23 = tanh2(f2{c[2], c[3]});
        pa = pkfma(w30a[mt], t01, pa);
        pa = pkfma(w30b[mt], t23, pa);
        pb = pkfma(w31a[mt], t01, pb);
        pb = pkfma(w31b[mt], t23, pb);
      }
      float p0 = pa.x + pa.y;
      float p1 = pb.x + pb.y;
      // quad butterfly: lanes col, col^16, col^32, col^48 hold the 4 row-quarters
      p0 += __shfl_xor(p0, 16); p1 += __shfl_xor(p1, 16);
      p0 += __shfl_xor(p0, 32); p1 += __shfl_xor(p1, 32);
      kx = p0 + b30;
      ky = p1 + b31;
    };

    EVAL(yx, yy, k1x, k1y);
    EVAL(fmaf(dt, A21 * k1x, yx), fmaf(dt, A21 * k1y, yy), k2x, k2y);
    {
      float cx = fmaf(A32, k2x, A31 * k1x);
      float cy = fmaf(A32, k2y, A31 * k1y);
      EVAL(fmaf(dt, cx, yx), fmaf(dt, cy, yy), k3x, k3y);
    }
    {
      float cx = fmaf(A43, k3x, fmaf(A42, k2x, A41 * k1x));
      float cy = fmaf(A43, k3y, fmaf(A42, k2y, A41 * k1y));
      EVAL(fmaf(dt, cx, yx), fmaf(dt, cy, yy), k4x, k4y);
    }
    {
      float cx = fmaf(A54, k4x, fmaf(A53, k3x, fmaf(A52, k2x, A51 * k1x)));
      float cy = fmaf(A54, k4y, fmaf(A53, k3y, fmaf(A52, k2y, A51 * k1y)));
      EVAL(fmaf(dt, cx, yx), fmaf(dt, cy, yy), k5x, k5y);
    }
    {
      float cx = fmaf(A65, k5x, fmaf(A64, k4x, fmaf(A63, k3x, fmaf(A62, k2x, A61 * k1x))));
      float cy = fmaf(A65, k5y, fmaf(A64, k4y, fmaf(A63, k3y, fmaf(A62, k2y, A61 * k1y))));
      EVAL(fmaf(dt, cx, yx), fmaf(dt, cy, yy), k6x, k6y);
    }
    {
      float cx = fmaf(BB6, k6x, fmaf(BB5, k5x, fmaf(BB4, k4x, fmaf(BB3, k3x, BB1 * k1x))));
      float cy = fmaf(BB6, k6y, fmaf(BB5, k5y, fmaf(BB4, k4y, fmaf(BB3, k3y, BB1 * k1y))));
      yx = fmaf(dt, cx, yx);
      yy = fmaf(dt, cy, yy);
    }
    if (quad == 0) outv[(t + 1) * NB + gb] = make_float2(yx, yy);
  }
}

extern "C" void kernel_launch(void* const* d_in, const int* in_sizes, int n_in,
                              void* d_out, int out_size, void* d_ws, size_t ws_size,
                              hipStream_t stream) {
  const float* y0 = (const float*)d_in[0];
  const float* ts = (const float*)d_in[1];
  const float* W1 = (const float*)d_in[2];
  const float* b1 = (const float*)d_in[3];
  const float* W2 = (const float*)d_in[4];
  const float* b2 = (const float*)d_in[5];
  const float* W3 = (const float*)d_in[6];
  const float* b3 = (const float*)d_in[7];
  float* out = (float*)d_out;

  // 256 blocks x 256 threads = 1024 waves (16 real cols each):
  // 1 wave/SIMD on all 256 CUs — proven-optimal geometry (r6 vs r8/r9).
  node_step_kernel<<<dim3(NB / 64), dim3(256), 0, stream>>>(
      y0, ts, W1, b1, W2, b2, W3, b3, out);
}

// Round 9
// 3468.681 us; speedup vs baseline: 1.8944x; 1.0172x over previous
//
#include <hip/hip_runtime.h>

#define NB 16384
#define NT 1024

typedef _Float16 h8  __attribute__((ext_vector_type(8)));
typedef __fp16   g2  __attribute__((ext_vector_type(2)));   // cvt_pkrtz result type
typedef float    f4  __attribute__((ext_vector_type(4)));
typedef float    f2  __attribute__((ext_vector_type(2)));   // v_pk_*_f32 operand

// AS4 scalar loads for wave-uniform data (ts).
typedef __attribute__((address_space(4))) const float cfloat;
static __device__ __forceinline__ const cfloat* as_const(const float* p) {
  return (const cfloat*)(unsigned long long)p;
}

#define TANH_SCALE 2.88539008177792681f  // 2*log2(e)

// Packed fma on f2 -> v_pk_fma_f32 (gfx950 packed FP32 VOP3P).
static __device__ __forceinline__ f2 pkfma(f2 a, f2 b, f2 c) {
#if __has_builtin(__builtin_elementwise_fma)
  return __builtin_elementwise_fma(a, b, c);
#else
  return a * b + c;   // pk_mul + pk_add fallback
#endif
}

// Packed "r-sigmoid" pair: r = rcp(1 + exp2(xs)). tanh(x) = 1 - 2r, but the
// affine (1, -2) is FOLDED INTO WEIGHTS at init (r18), so r is consumed raw.
// 2 v_exp + 1 pk_add + 2 v_rcp (the old final pk_fma is gone).
static __device__ __forceinline__ f2 rsig2(f2 xs) {
  const float e0 = __builtin_amdgcn_exp2f(xs.x);
  const float e1 = __builtin_amdgcn_exp2f(xs.y);
  const f2 d = f2{e0, e1} + 1.0f;                       // v_pk_add_f32
  return f2{ __builtin_amdgcn_rcpf(d.x), __builtin_amdgcn_rcpf(d.y) };
}

union H8U { h8 v; g2 p[4]; };  // type-pun: 4 packed pairs <-> one MFMA operand

// Pin into VGPR (generous budget required: min_waves=1; r7 proved tight bounds
// re-trigger in-loop rematerialization of the W2 loads -> 34.8 GB FETCH).
#define PINV(x)  asm volatile("" : "+v"(x))

// ---- Round 18 = r17 + affine fold (tanh = 1-2r into weights) + f4 accb ----
// r17 ledger: ~880 cyc/eval = trans 465 (floor) + full-rate 160 + MFMA 84 +
// stall 170. This round deletes 16 pk_fma (tanh final stage, both layers) via
// init-time algebra: B-operand carries r with A* = -2*TS*W2 and accb* =
// TS*(b2 + rowsum(W2)); L3 accumulates q = sum(w3*r), k = w3s - 2q with
// w3s = sum(w3)+b3 wave-uniform. Plus accb as plain f4 (r14-proven) so MFMA
// reads C directly -> kills 16 v_mov/eval. ~-32 slots ~= -7%.
// Precision: B-side quant err doubles (r vs h1 under the x2) -> absmax <~2x.
__global__ __launch_bounds__(256, 1)
void node_step_kernel(const float* __restrict__ y0,
                      const float* __restrict__ ts,
                      const float* __restrict__ W1,
                      const float* __restrict__ b1,
                      const float* __restrict__ W2,
                      const float* __restrict__ b2,
                      const float* __restrict__ W3,
                      const float* __restrict__ b3,
                      float* __restrict__ out)
{
  const int lane = (int)(threadIdx.x & 63);
  const int wv   = (int)(threadIdx.x >> 6);   // 0..3
  const int col  = lane & 15;                 // batch column within wave
  const int quad = lane >> 4;
  const int gb   = (int)blockIdx.x * 64 + wv * 16 + col;

  // ---- init: W2 A-fragments x (-2*TANH_SCALE), plain f16, pinned ----
  // A-frag (HW-verified r5/r6): A[m = lane&15][k = quad*8 + j]; k-step adds 32.
  const float ASCALE = -2.0f * TANH_SCALE;
  h8 Ah[4][2];                                // [mtile][kstep]
#pragma unroll
  for (int mt = 0; mt < 4; ++mt) {
    const int m = mt * 16 + col;
#pragma unroll
    for (int ks = 0; ks < 2; ++ks) {
      const float* wp = W2 + m * 64 + ks * 32 + quad * 8;
      H8U hu;
#pragma unroll
      for (int p = 0; p < 4; ++p)
        hu.p[p] = __builtin_amdgcn_cvt_pkrtz(wp[2*p]     * ASCALE,
                                             wp[2*p + 1] * ASCALE);
      Ah[mt][ks] = hu.v;  PINV(Ah[mt][ks]);
    }
  }

  // accb* = TANH_SCALE*(b2 + rowsum(W2)) in C/D layout, as plain f4 (r14-
  // proven; MFMA consumes directly as C -> no per-eval movs). W3 rows pair-
  // grouped for packed L3 accumulation of q = sum(w3*r).
  f4 accb4[4];
  f2 w30a[4], w30b[4], w31a[4], w31b[4];
#pragma unroll
  for (int mt = 0; mt < 4; ++mt) {
#pragma unroll
    for (int r = 0; r < 4; ++r) {
      const int m = mt * 16 + quad * 4 + r;
      float rs = 0.0f;
      const float* wr = W2 + m * 64;
#pragma unroll
      for (int k = 0; k < 64; ++k) rs += wr[k];
      accb4[mt][r] = (b2[m] + rs) * TANH_SCALE;
    }
    const int j2 = mt * 16 + quad * 4;
    w30a[mt] = f2{W3[j2 + 0],      W3[j2 + 1]};       PINV(w30a[mt]);
    w30b[mt] = f2{W3[j2 + 2],      W3[j2 + 3]};       PINV(w30b[mt]);
    w31a[mt] = f2{W3[64 + j2 + 0], W3[64 + j2 + 1]};  PINV(w31a[mt]);
    w31b[mt] = f2{W3[64 + j2 + 2], W3[64 + j2 + 3]};  PINV(w31b[mt]);
  }

  // Wave-uniform finishers: w3s = sum_rows(W3) + b3 (k = w3s - 2*q_total).
  float w3s0 = b3[0], w3s1 = b3[1];
#pragma unroll
  for (int k = 0; k < 64; ++k) { w3s0 += W3[k]; w3s1 += W3[64 + k]; }

  // L1 weights (x TANH_SCALE) as f2 pairs; pair p covers B-fragment elements
  // (2p, 2p+1): p<4 -> rows quad*8+{2p,2p+1} (kstep0); p>=4 -> rows
  // 32+quad*8+{2p-8,2p-7} (kstep1). Pairs never straddle the kstep boundary.
  f2 w1a2[8], w1b2[8], b1r2[8];
#pragma unroll
  for (int p = 0; p < 8; ++p) {
    const int e0 = 2 * p;
    const int row0 = (e0 < 8) ? (quad * 8 + e0) : (32 + quad * 8 + (e0 - 8));
    const int row1 = row0 + 1;
    w1a2[p] = f2{W1[2 * row0],     W1[2 * row1]}     * TANH_SCALE;  PINV(w1a2[p]);
    w1b2[p] = f2{W1[2 * row0 + 1], W1[2 * row1 + 1]} * TANH_SCALE;  PINV(w1b2[p]);
    b1r2[p] = f2{b1[row0],         b1[row1]}         * TANH_SCALE;  PINV(b1r2[p]);
  }
  const cfloat* tsc = as_const(ts);

  float yx = y0[2 * gb], yy = y0[2 * gb + 1];

  float2* __restrict__ outv = (float2*)out;
  if (quad == 0) outv[gb] = make_float2(yx, yy);   // SaveAt includes t0

  const float A21 = (float)(1.0/5.0);
  const float A31 = (float)(3.0/40.0),  A32 = (float)(9.0/40.0);
  const float A41 = (float)(44.0/45.0), A42 = (float)(-56.0/15.0), A43 = (float)(32.0/9.0);
  const float A51 = (float)(19372.0/6561.0), A52 = (float)(-25360.0/2187.0),
              A53 = (float)(64448.0/6561.0), A54 = (float)(-212.0/729.0);
  const float A61 = (float)(9017.0/3168.0), A62 = (float)(-355.0/33.0),
              A63 = (float)(46732.0/5247.0), A64 = (float)(49.0/176.0),
              A65 = (float)(-5103.0/18656.0);
  const float BB1 = (float)(35.0/384.0), BB3 = (float)(500.0/1113.0),
              BB4 = (float)(125.0/192.0), BB5 = (float)(-2187.0/6784.0),
              BB6 = (float)(11.0/84.0);

  float k1x,k1y,k2x,k2y,k3x,k3y,k4x,k4y,k5x,k5y,k6x,k6y;

  for (int t = 0; t < NT - 1; ++t) {
    const float dt = tsc[t + 1] - tsc[t];

    auto EVAL = [&](float ysx, float ysy, float& kx, float& ky) {
      // ---- L1: 8 preact pairs (2 pk_fma each) + 8 packed r-sigmoid pairs ----
      const f2 ysx2 = {ysx, ysx}, ysy2 = {ysy, ysy};
      f2 hv2[8];
#pragma unroll
      for (int p = 0; p < 8; ++p)
        hv2[p] = rsig2(pkfma(w1a2[p], ysx2, pkfma(w1b2[p], ysy2, b1r2[p])));

      // pair-pack r into B-fragments (affine handled by A*/accb*)
      H8U BH0, BH1;
#pragma unroll
      for (int p = 0; p < 4; ++p) {
        BH0.p[p] = __builtin_amdgcn_cvt_pkrtz(hv2[p].x,     hv2[p].y);
        BH1.p[p] = __builtin_amdgcn_cvt_pkrtz(hv2[4 + p].x, hv2[4 + p].y);
      }

      // ---- L2: 4 m-tiles x 2 k-steps; C = accb* directly (f4, no movs) ----
      // ---- L3: packed r-sigmoid on acc pairs + packed q accumulation ----
      f2 pa = {0.0f, 0.0f}, pb = {0.0f, 0.0f};   // q-partials for out0 / out1
#pragma unroll
      for (int mt = 0; mt < 4; ++mt) {
        f4 c = __builtin_amdgcn_mfma_f32_16x16x32_f16(Ah[mt][0], BH0.v, accb4[mt], 0, 0, 0);
        c = __builtin_amdgcn_mfma_f32_16x16x32_f16(Ah[mt][1], BH1.v, c, 0, 0, 0);
        const f2 t01 = rsig2(f2{c[0], c[1]});
        const f2 t23 = rsig2(f2{c[2], c[3]});
        pa = pkfma(w30a[mt], t01, pa);
        pa = pkfma(w30b[mt], t23, pa);
        pb = pkfma(w31a[mt], t01, pb);
        pb = pkfma(w31b[mt], t23, pb);
      }
      float p0 = pa.x + pa.y;
      float p1 = pb.x + pb.y;
      // quad butterfly: lanes col, col^16, col^32, col^48 hold the 4 row-quarters
      p0 += __shfl_xor(p0, 16); p1 += __shfl_xor(p1, 16);
      p0 += __shfl_xor(p0, 32); p1 += __shfl_xor(p1, 32);
      kx = fmaf(-2.0f, p0, w3s0);   // k = sum(w3) + b3 - 2*q
      ky = fmaf(-2.0f, p1, w3s1);
    };

    EVAL(yx, yy, k1x, k1y);
    EVAL(fmaf(dt, A21 * k1x, yx), fmaf(dt, A21 * k1y, yy), k2x, k2y);
    {
      float cx = fmaf(A32, k2x, A31 * k1x);
      float cy = fmaf(A32, k2y, A31 * k1y);
      EVAL(fmaf(dt, cx, yx), fmaf(dt, cy, yy), k3x, k3y);
    }
    {
      float cx = fmaf(A43, k3x, fmaf(A42, k2x, A41 * k1x));
      float cy = fmaf(A43, k3y, fmaf(A42, k2y, A41 * k1y));
      EVAL(fmaf(dt, cx, yx), fmaf(dt, cy, yy), k4x, k4y);
    }
    {
      float cx = fmaf(A54, k4x, fmaf(A53, k3x, fmaf(A52, k2x, A51 * k1x)));
      float cy = fmaf(A54, k4y, fmaf(A53, k3y, fmaf(A52, k2y, A51 * k1y)));
      EVAL(fmaf(dt, cx, yx), fmaf(dt, cy, yy), k5x, k5y);
    }
    {
      float cx = fmaf(A65, k5x, fmaf(A64, k4x, fmaf(A63, k3x, fmaf(A62, k2x, A61 * k1x))));
      float cy = fmaf(A65, k5y, fmaf(A64, k4y, fmaf(A63, k3y, fmaf(A62, k2y, A61 * k1y))));
      EVAL(fmaf(dt, cx, yx), fmaf(dt, cy, yy), k6x, k6y);
    }
    {
      float cx = fmaf(BB6, k6x, fmaf(BB5, k5x, fmaf(BB4, k4x, fmaf(BB3, k3x, BB1 * k1x))));
      float cy = fmaf(BB6, k6y, fmaf(BB5, k5y, fmaf(BB4, k4y, fmaf(BB3, k3y, BB1 * k1y))));
      yx = fmaf(dt, cx, yx);
      yy = fmaf(dt, cy, yy);
    }
    if (quad == 0) outv[(t + 1) * NB + gb] = make_float2(yx, yy);
  }
}

extern "C" void kernel_launch(void* const* d_in, const int* in_sizes, int n_in,
                              void* d_out, int out_size, void* d_ws, size_t ws_size,
                              hipStream_t stream) {
  const float* y0 = (const float*)d_in[0];
  const float* ts = (const float*)d_in[1];
  const float* W1 = (const float*)d_in[2];
  const float* b1 = (const float*)d_in[3];
  const float* W2 = (const float*)d_in[4];
  const float* b2 = (const float*)d_in[5];
  const float* W3 = (const float*)d_in[6];
  const float* b3 = (const float*)d_in[7];
  float* out = (float*)d_out;

  // 256 blocks x 256 threads = 1024 waves (16 real cols each):
  // 1 wave/SIMD on all 256 CUs — proven-optimal geometry (r6 vs r8/r9).
  node_step_kernel<<<dim3(NB / 64), dim3(256), 0, stream>>>(
      y0, ts, W1, b1, W2, b2, W3, b3, out);
}

// Round 10
// 3436.270 us; speedup vs baseline: 1.9122x; 1.0094x over previous
//
#include <hip/hip_runtime.h>

#define NB 16384
#define NT 1024

typedef _Float16 h8  __attribute__((ext_vector_type(8)));
typedef __fp16   g2  __attribute__((ext_vector_type(2)));   // cvt_pkrtz result type
typedef float    f4  __attribute__((ext_vector_type(4)));
typedef float    f2  __attribute__((ext_vector_type(2)));   // v_pk_*_f32 operand

// AS4 scalar loads for wave-uniform data (ts).
typedef __attribute__((address_space(4))) const float cfloat;
static __device__ __forceinline__ const cfloat* as_const(const float* p) {
  return (const cfloat*)(unsigned long long)p;
}

#define TANH_SCALE 2.88539008177792681f  // 2*log2(e)

// Packed fma on f2 -> v_pk_fma_f32 (gfx950 packed FP32 VOP3P).
static __device__ __forceinline__ f2 pkfma(f2 a, f2 b, f2 c) {
#if __has_builtin(__builtin_elementwise_fma)
  return __builtin_elementwise_fma(a, b, c);
#else
  return a * b + c;   // pk_mul + pk_add fallback
#endif
}

// Packed "r-sigmoid" pair: r = rcp(1 + exp2(xs)). tanh(x) = 1 - 2r; the
// affine (1, -2) is FOLDED INTO WEIGHTS at init (r18), so r is consumed raw.
// 2 v_exp + 1 pk_add + 2 v_rcp.
static __device__ __forceinline__ f2 rsig2(f2 xs) {
  const float e0 = __builtin_amdgcn_exp2f(xs.x);
  const float e1 = __builtin_amdgcn_exp2f(xs.y);
  const f2 d = f2{e0, e1} + 1.0f;                       // v_pk_add_f32
  return f2{ __builtin_amdgcn_rcpf(d.x), __builtin_amdgcn_rcpf(d.y) };
}

union H8U { h8 v; g2 p[4]; };  // type-pun: 4 packed pairs <-> one MFMA operand

// Pin into VGPR (generous budget required: min_waves=1; r7 proved tight bounds
// re-trigger in-loop rematerialization of the W2 loads -> 34.8 GB FETCH).
#define PINV(x)  asm volatile("" : "+v"(x))

// ---- Round 19 = r18 with a REGISTER-LIGHT INIT (loop body untouched) ----
// r18's rowsum init (16 rows x 64 fully-unrolled scalar loads) blew the
// allocator to VGPR=256 and produced ~280 MB/dispatch of scratch traffic
// (FETCH 92.7 MB, WRITE +184 MB) — spill VMEM ops ate most of the affine-fold
// gain. This round: float4 rowsum with #pragma unroll 1 (live set ~2 float4),
// unroll-1 w3s loop. Everything in the t-loop is byte-identical to r18.
__global__ __launch_bounds__(256, 1)
void node_step_kernel(const float* __restrict__ y0,
                      const float* __restrict__ ts,
                      const float* __restrict__ W1,
                      const float* __restrict__ b1,
                      const float* __restrict__ W2,
                      const float* __restrict__ b2,
                      const float* __restrict__ W3,
                      const float* __restrict__ b3,
                      float* __restrict__ out)
{
  const int lane = (int)(threadIdx.x & 63);
  const int wv   = (int)(threadIdx.x >> 6);   // 0..3
  const int col  = lane & 15;                 // batch column within wave
  const int quad = lane >> 4;
  const int gb   = (int)blockIdx.x * 64 + wv * 16 + col;

  // ---- init: W2 A-fragments x (-2*TANH_SCALE), plain f16, pinned ----
  // A-frag (HW-verified r5/r6): A[m = lane&15][k = quad*8 + j]; k-step adds 32.
  const float ASCALE = -2.0f * TANH_SCALE;
  h8 Ah[4][2];                                // [mtile][kstep]
#pragma unroll
  for (int mt = 0; mt < 4; ++mt) {
    const int m = mt * 16 + col;
#pragma unroll
    for (int ks = 0; ks < 2; ++ks) {
      const float* wp = W2 + m * 64 + ks * 32 + quad * 8;
      H8U hu;
#pragma unroll
      for (int p = 0; p < 4; ++p)
        hu.p[p] = __builtin_amdgcn_cvt_pkrtz(wp[2*p]     * ASCALE,
                                             wp[2*p + 1] * ASCALE);
      Ah[mt][ks] = hu.v;  PINV(Ah[mt][ks]);
    }
  }

  // accb* = TANH_SCALE*(b2 + rowsum(W2)) in C/D layout as plain f4.
  // Register-light: float4 loads, unroll-1 accumulation loop.
  f4 accb4[4];
#pragma unroll
  for (int mt = 0; mt < 4; ++mt) {
#pragma unroll
    for (int r = 0; r < 4; ++r) {
      const int m = mt * 16 + quad * 4 + r;
      const float4* wr = (const float4*)(W2 + m * 64);
      float4 s = wr[0];
#pragma unroll 1
      for (int k = 1; k < 16; ++k) {
        const float4 v = wr[k];
        s.x += v.x; s.y += v.y; s.z += v.z; s.w += v.w;
      }
      accb4[mt][r] = (b2[m] + (s.x + s.y) + (s.z + s.w)) * TANH_SCALE;
    }
  }

  // W3 rows in C/D layout, pair-grouped for packed q accumulation.
  f2 w30a[4], w30b[4], w31a[4], w31b[4];
#pragma unroll
  for (int mt = 0; mt < 4; ++mt) {
    const int j2 = mt * 16 + quad * 4;
    w30a[mt] = f2{W3[j2 + 0],      W3[j2 + 1]};       PINV(w30a[mt]);
    w30b[mt] = f2{W3[j2 + 2],      W3[j2 + 3]};       PINV(w30b[mt]);
    w31a[mt] = f2{W3[64 + j2 + 0], W3[64 + j2 + 1]};  PINV(w31a[mt]);
    w31b[mt] = f2{W3[64 + j2 + 2], W3[64 + j2 + 3]};  PINV(w31b[mt]);
  }

  // Wave-uniform finishers: w3s = sum_rows(W3) + b3 (k = w3s - 2*q_total).
  float w3s0 = b3[0], w3s1 = b3[1];
#pragma unroll 1
  for (int k = 0; k < 64; ++k) { w3s0 += W3[k]; w3s1 += W3[64 + k]; }

  // L1 weights (x TANH_SCALE) as f2 pairs; pair p covers B-fragment elements
  // (2p, 2p+1): p<4 -> rows quad*8+{2p,2p+1} (kstep0); p>=4 -> rows
  // 32+quad*8+{2p-8,2p-7} (kstep1). Pairs never straddle the kstep boundary.
  f2 w1a2[8], w1b2[8], b1r2[8];
#pragma unroll
  for (int p = 0; p < 8; ++p) {
    const int e0 = 2 * p;
    const int row0 = (e0 < 8) ? (quad * 8 + e0) : (32 + quad * 8 + (e0 - 8));
    const int row1 = row0 + 1;
    w1a2[p] = f2{W1[2 * row0],     W1[2 * row1]}     * TANH_SCALE;  PINV(w1a2[p]);
    w1b2[p] = f2{W1[2 * row0 + 1], W1[2 * row1 + 1]} * TANH_SCALE;  PINV(w1b2[p]);
    b1r2[p] = f2{b1[row0],         b1[row1]}         * TANH_SCALE;  PINV(b1r2[p]);
  }
  const cfloat* tsc = as_const(ts);

  float yx = y0[2 * gb], yy = y0[2 * gb + 1];

  float2* __restrict__ outv = (float2*)out;
  if (quad == 0) outv[gb] = make_float2(yx, yy);   // SaveAt includes t0

  const float A21 = (float)(1.0/5.0);
  const float A31 = (float)(3.0/40.0),  A32 = (float)(9.0/40.0);
  const float A41 = (float)(44.0/45.0), A42 = (float)(-56.0/15.0), A43 = (float)(32.0/9.0);
  const float A51 = (float)(19372.0/6561.0), A52 = (float)(-25360.0/2187.0),
              A53 = (float)(64448.0/6561.0), A54 = (float)(-212.0/729.0);
  const float A61 = (float)(9017.0/3168.0), A62 = (float)(-355.0/33.0),
              A63 = (float)(46732.0/5247.0), A64 = (float)(49.0/176.0),
              A65 = (float)(-5103.0/18656.0);
  const float BB1 = (float)(35.0/384.0), BB3 = (float)(500.0/1113.0),
              BB4 = (float)(125.0/192.0), BB5 = (float)(-2187.0/6784.0),
              BB6 = (float)(11.0/84.0);

  float k1x,k1y,k2x,k2y,k3x,k3y,k4x,k4y,k5x,k5y,k6x,k6y;

  for (int t = 0; t < NT - 1; ++t) {
    const float dt = tsc[t + 1] - tsc[t];

    auto EVAL = [&](float ysx, float ysy, float& kx, float& ky) {
      // ---- L1: 8 preact pairs (2 pk_fma each) + 8 packed r-sigmoid pairs ----
      const f2 ysx2 = {ysx, ysx}, ysy2 = {ysy, ysy};
      f2 hv2[8];
#pragma unroll
      for (int p = 0; p < 8; ++p)
        hv2[p] = rsig2(pkfma(w1a2[p], ysx2, pkfma(w1b2[p], ysy2, b1r2[p])));

      // pair-pack r into B-fragments (affine handled by A*/accb*)
      H8U BH0, BH1;
#pragma unroll
      for (int p = 0; p < 4; ++p) {
        BH0.p[p] = __builtin_amdgcn_cvt_pkrtz(hv2[p].x,     hv2[p].y);
        BH1.p[p] = __builtin_amdgcn_cvt_pkrtz(hv2[4 + p].x, hv2[4 + p].y);
      }

      // ---- L2: 4 m-tiles x 2 k-steps; C = accb* directly (f4, no movs) ----
      // ---- L3: packed r-sigmoid on acc pairs + packed q accumulation ----
      f2 pa = {0.0f, 0.0f}, pb = {0.0f, 0.0f};   // q-partials for out0 / out1
#pragma unroll
      for (int mt = 0; mt < 4; ++mt) {
        f4 c = __builtin_amdgcn_mfma_f32_16x16x32_f16(Ah[mt][0], BH0.v, accb4[mt], 0, 0, 0);
        c = __builtin_amdgcn_mfma_f32_16x16x32_f16(Ah[mt][1], BH1.v, c, 0, 0, 0);
        const f2 t01 = rsig2(f2{c[0], c[1]});
        const f2 t23 = rsig2(f2{c[2], c[3]});
        pa = pkfma(w30a[mt], t01, pa);
        pa = pkfma(w30b[mt], t23, pa);
        pb = pkfma(w31a[mt], t01, pb);
        pb = pkfma(w31b[mt], t23, pb);
      }
      float p0 = pa.x + pa.y;
      float p1 = pb.x + pb.y;
      // quad butterfly: lanes col, col^16, col^32, col^48 hold the 4 row-quarters
      p0 += __shfl_xor(p0, 16); p1 += __shfl_xor(p1, 16);
      p0 += __shfl_xor(p0, 32); p1 += __shfl_xor(p1, 32);
      kx = fmaf(-2.0f, p0, w3s0);   // k = sum(w3) + b3 - 2*q
      ky = fmaf(-2.0f, p1, w3s1);
    };

    EVAL(yx, yy, k1x, k1y);
    EVAL(fmaf(dt, A21 * k1x, yx), fmaf(dt, A21 * k1y, yy), k2x, k2y);
    {
      float cx = fmaf(A32, k2x, A31 * k1x);
      float cy = fmaf(A32, k2y, A31 * k1y);
      EVAL(fmaf(dt, cx, yx), fmaf(dt, cy, yy), k3x, k3y);
    }
    {
      float cx = fmaf(A43, k3x, fmaf(A42, k2x, A41 * k1x));
      float cy = fmaf(A43, k3y, fmaf(A42, k2y, A41 * k1y));
      EVAL(fmaf(dt, cx, yx), fmaf(dt, cy, yy), k4x, k4y);
    }
    {
      float cx = fmaf(A54, k4x, fmaf(A53, k3x, fmaf(A52, k2x, A51 * k1x)));
      float cy = fmaf(A54, k4y, fmaf(A53, k3y, fmaf(A52, k2y, A51 * k1y)));
      EVAL(fmaf(dt, cx, yx), fmaf(dt, cy, yy), k5x, k5y);
    }
    {
      float cx = fmaf(A65, k5x, fmaf(A64, k4x, fmaf(A63, k3x, fmaf(A62, k2x, A61 * k1x))));
      float cy = fmaf(A65, k5y, fmaf(A64, k4y, fmaf(A63, k3y, fmaf(A62, k2y, A61 * k1y))));
      EVAL(fmaf(dt, cx, yx), fmaf(dt, cy, yy), k6x, k6y);
    }
    {
      float cx = fmaf(BB6, k6x, fmaf(BB5, k5x, fmaf(BB4, k4x, fmaf(BB3, k3x, BB1 * k1x))));
      float cy = fmaf(BB6, k6y, fmaf(BB5, k5y, fmaf(BB4, k4y, fmaf(BB3, k3y, BB1 * k1y))));
      yx = fmaf(dt, cx, yx);
      yy = fmaf(dt, cy, yy);
    }
    if (quad == 0) outv[(t + 1) * NB + gb] = make_float2(yx, yy);
  }
}

extern "C" void kernel_launch(void* const* d_in, const int* in_sizes, int n_in,
                              void* d_out, int out_size, void* d_ws, size_t ws_size,
                              hipStream_t stream) {
  const float* y0 = (const float*)d_in[0];
  const float* ts = (const float*)d_in[1];
  const float* W1 = (const float*)d_in[2];
  const float* b1 = (const float*)d_in[3];
  const float* W2 = (const float*)d_in[4];
  const float* b2 = (const float*)d_in[5];
  const float* W3 = (const float*)d_in[6];
  const float* b3 = (const float*)d_in[7];
  float* out = (float*)d_out;

  // 256 blocks x 256 threads = 1024 waves (16 real cols each):
  // 1 wave/SIMD on all 256 CUs — proven-optimal geometry (r6 vs r8/r9).
  node_step_kernel<<<dim3(NB / 64), dim3(256), 0, stream>>>(
      y0, ts, W1, b1, W2, b2, W3, b3, out);
}

// Round 12
// 3270.866 us; speedup vs baseline: 2.0089x; 1.0506x over previous
//
#include <hip/hip_runtime.h>

#define NB 16384
#define NT 1024

typedef _Float16 h8  __attribute__((ext_vector_type(8)));
typedef __fp16   g2  __attribute__((ext_vector_type(2)));   // cvt_pkrtz result type
typedef float    f4  __attribute__((ext_vector_type(4)));
typedef float    f2  __attribute__((ext_vector_type(2)));   // v_pk_*_f32 operand

// AS4 scalar loads for wave-uniform data (ts).
typedef __attribute__((address_space(4))) const float cfloat;
static __device__ __forceinline__ const cfloat* as_const(const float* p) {
  return (const cfloat*)(unsigned long long)p;
}

#define TANH_SCALE 2.88539008177792681f  // 2*log2(e)

// Packed fma on f2 -> v_pk_fma_f32 (gfx950 packed FP32 VOP3P).
static __device__ __forceinline__ f2 pkfma(f2 a, f2 b, f2 c) {
#if __has_builtin(__builtin_elementwise_fma)
  return __builtin_elementwise_fma(a, b, c);
#else
  return a * b + c;   // pk_mul + pk_add fallback
#endif
}

// Packed "r-sigmoid" pair: r = rcp(1 + exp2(xs)). tanh(x) = 1 - 2r; the
// affine (1, -2) is FOLDED INTO WEIGHTS at init (r18), so r is consumed raw.
static __device__ __forceinline__ f2 rsig2(f2 xs) {
  const float e0 = __builtin_amdgcn_exp2f(xs.x);
  const float e1 = __builtin_amdgcn_exp2f(xs.y);
  const f2 d = f2{e0, e1} + 1.0f;                       // v_pk_add_f32
  return f2{ __builtin_amdgcn_rcpf(d.x), __builtin_amdgcn_rcpf(d.y) };
}

union H8U { h8 v; g2 p[4]; };  // type-pun: 4 packed pairs <-> one MFMA operand

// Pin into VGPR (generous budget required: min_waves=1; r7 proved tight bounds
// re-trigger in-loop rematerialization of the W2 loads -> 34.8 GB FETCH).
#define PINV(x)  asm volatile("" : "+v"(x))

// ---- Round 21 = r19 + FLAT quad butterfly (permlane is dead: r12+r20) ----
// r20 (permlane16/32_swap qsum) failed absmax 3425 even isolated — consistent
// with operand aliasing on the in-place swap (same SSA value -> same physical
// VGPR -> self-swap -> sum = 2*p[l^16]). Primitive abandoned. This round
// attacks the same exposed DS latency with PROVEN __shfl_xor only: flatten
// the 2-deep chain (shfl16,add,shfl32,add = 2 latency windows) into a 1-deep
// 3-wide butterfly (shfl16 + shfl32 + shfl48, all 6 swizzles pipelined in one
// window). +2 issue slots, ~-40..50 cyc exposed latency per eval.
// Re-association changes the last bit at most; absmax ~0.0156-0.031 << 0.08.
__global__ __launch_bounds__(256, 1)
void node_step_kernel(const float* __restrict__ y0,
                      const float* __restrict__ ts,
                      const float* __restrict__ W1,
                      const float* __restrict__ b1,
                      const float* __restrict__ W2,
                      const float* __restrict__ b2,
                      const float* __restrict__ W3,
                      const float* __restrict__ b3,
                      float* __restrict__ out)
{
  const int lane = (int)(threadIdx.x & 63);
  const int wv   = (int)(threadIdx.x >> 6);   // 0..3
  const int col  = lane & 15;                 // batch column within wave
  const int quad = lane >> 4;
  const int gb   = (int)blockIdx.x * 64 + wv * 16 + col;

  // ---- init: W2 A-fragments x (-2*TANH_SCALE), plain f16, pinned ----
  // A-frag (HW-verified r5/r6): A[m = lane&15][k = quad*8 + j]; k-step adds 32.
  const float ASCALE = -2.0f * TANH_SCALE;
  h8 Ah[4][2];                                // [mtile][kstep]
#pragma unroll
  for (int mt = 0; mt < 4; ++mt) {
    const int m = mt * 16 + col;
#pragma unroll
    for (int ks = 0; ks < 2; ++ks) {
      const float* wp = W2 + m * 64 + ks * 32 + quad * 8;
      H8U hu;
#pragma unroll
      for (int p = 0; p < 4; ++p)
        hu.p[p] = __builtin_amdgcn_cvt_pkrtz(wp[2*p]     * ASCALE,
                                             wp[2*p + 1] * ASCALE);
      Ah[mt][ks] = hu.v;  PINV(Ah[mt][ks]);
    }
  }

  // accb* = TANH_SCALE*(b2 + rowsum(W2)) in C/D layout as plain f4.
  // Register-light (r19): float4 loads, unroll-1 accumulation loop.
  f4 accb4[4];
#pragma unroll
  for (int mt = 0; mt < 4; ++mt) {
#pragma unroll
    for (int r = 0; r < 4; ++r) {
      const int m = mt * 16 + quad * 4 + r;
      const float4* wr = (const float4*)(W2 + m * 64);
      float4 s = wr[0];
#pragma unroll 1
      for (int k = 1; k < 16; ++k) {
        const float4 v = wr[k];
        s.x += v.x; s.y += v.y; s.z += v.z; s.w += v.w;
      }
      accb4[mt][r] = (b2[m] + (s.x + s.y) + (s.z + s.w)) * TANH_SCALE;
    }
  }

  // W3 rows in C/D layout, pair-grouped for packed q accumulation.
  f2 w30a[4], w30b[4], w31a[4], w31b[4];
#pragma unroll
  for (int mt = 0; mt < 4; ++mt) {
    const int j2 = mt * 16 + quad * 4;
    w30a[mt] = f2{W3[j2 + 0],      W3[j2 + 1]};       PINV(w30a[mt]);
    w30b[mt] = f2{W3[j2 + 2],      W3[j2 + 3]};       PINV(w30b[mt]);
    w31a[mt] = f2{W3[64 + j2 + 0], W3[64 + j2 + 1]};  PINV(w31a[mt]);
    w31b[mt] = f2{W3[64 + j2 + 2], W3[64 + j2 + 3]};  PINV(w31b[mt]);
  }

  // Wave-uniform finishers: w3s = sum_rows(W3) + b3 (k = w3s - 2*q_total).
  float w3s0 = b3[0], w3s1 = b3[1];
#pragma unroll 1
  for (int k = 0; k < 64; ++k) { w3s0 += W3[k]; w3s1 += W3[64 + k]; }

  // L1 weights (x TANH_SCALE) as f2 pairs; pair p covers B-fragment elements
  // (2p, 2p+1): p<4 -> rows quad*8+{2p,2p+1} (kstep0); p>=4 -> rows
  // 32+quad*8+{2p-8,2p-7} (kstep1). Pairs never straddle the kstep boundary.
  f2 w1a2[8], w1b2[8], b1r2[8];
#pragma unroll
  for (int p = 0; p < 8; ++p) {
    const int e0 = 2 * p;
    const int row0 = (e0 < 8) ? (quad * 8 + e0) : (32 + quad * 8 + (e0 - 8));
    const int row1 = row0 + 1;
    w1a2[p] = f2{W1[2 * row0],     W1[2 * row1]}     * TANH_SCALE;  PINV(w1a2[p]);
    w1b2[p] = f2{W1[2 * row0 + 1], W1[2 * row1 + 1]} * TANH_SCALE;  PINV(w1b2[p]);
    b1r2[p] = f2{b1[row0],         b1[row1]}         * TANH_SCALE;  PINV(b1r2[p]);
  }
  const cfloat* tsc = as_const(ts);

  float yx = y0[2 * gb], yy = y0[2 * gb + 1];

  float2* __restrict__ outv = (float2*)out;
  if (quad == 0) outv[gb] = make_float2(yx, yy);   // SaveAt includes t0

  const float A21 = (float)(1.0/5.0);
  const float A31 = (float)(3.0/40.0),  A32 = (float)(9.0/40.0);
  const float A41 = (float)(44.0/45.0), A42 = (float)(-56.0/15.0), A43 = (float)(32.0/9.0);
  const float A51 = (float)(19372.0/6561.0), A52 = (float)(-25360.0/2187.0),
              A53 = (float)(64448.0/6561.0), A54 = (float)(-212.0/729.0);
  const float A61 = (float)(9017.0/3168.0), A62 = (float)(-355.0/33.0),
              A63 = (float)(46732.0/5247.0), A64 = (float)(49.0/176.0),
              A65 = (float)(-5103.0/18656.0);
  const float BB1 = (float)(35.0/384.0), BB3 = (float)(500.0/1113.0),
              BB4 = (float)(125.0/192.0), BB5 = (float)(-2187.0/6784.0),
              BB6 = (float)(11.0/84.0);

  float k1x,k1y,k2x,k2y,k3x,k3y,k4x,k4y,k5x,k5y,k6x,k6y;

  for (int t = 0; t < NT - 1; ++t) {
    const float dt = tsc[t + 1] - tsc[t];

    auto EVAL = [&](float ysx, float ysy, float& kx, float& ky) {
      // ---- L1: 8 preact pairs (2 pk_fma each) + 8 packed r-sigmoid pairs ----
      const f2 ysx2 = {ysx, ysx}, ysy2 = {ysy, ysy};
      f2 hv2[8];
#pragma unroll
      for (int p = 0; p < 8; ++p)
        hv2[p] = rsig2(pkfma(w1a2[p], ysx2, pkfma(w1b2[p], ysy2, b1r2[p])));

      // pair-pack r into B-fragments (affine handled by A*/accb*)
      H8U BH0, BH1;
#pragma unroll
      for (int p = 0; p < 4; ++p) {
        BH0.p[p] = __builtin_amdgcn_cvt_pkrtz(hv2[p].x,     hv2[p].y);
        BH1.p[p] = __builtin_amdgcn_cvt_pkrtz(hv2[4 + p].x, hv2[4 + p].y);
      }

      // ---- L2: 4 m-tiles x 2 k-steps; C = accb* directly (f4, no movs) ----
      // ---- L3: packed r-sigmoid on acc pairs + packed q accumulation ----
      f2 pa = {0.0f, 0.0f}, pb = {0.0f, 0.0f};   // q-partials for out0 / out1
#pragma unroll
      for (int mt = 0; mt < 4; ++mt) {
        f4 c = __builtin_amdgcn_mfma_f32_16x16x32_f16(Ah[mt][0], BH0.v, accb4[mt], 0, 0, 0);
        c = __builtin_amdgcn_mfma_f32_16x16x32_f16(Ah[mt][1], BH1.v, c, 0, 0, 0);
        const f2 t01 = rsig2(f2{c[0], c[1]});
        const f2 t23 = rsig2(f2{c[2], c[3]});
        pa = pkfma(w30a[mt], t01, pa);
        pa = pkfma(w30b[mt], t23, pa);
        pb = pkfma(w31a[mt], t01, pb);
        pb = pkfma(w31b[mt], t23, pb);
      }
      const float p0 = pa.x + pa.y;
      const float p1 = pb.x + pb.y;
      // FLAT quad butterfly: 1 latency window, 6 pipelined ds ops total.
      const float q0 = ((p0 + __shfl_xor(p0, 16)) +
                        (__shfl_xor(p0, 32) + __shfl_xor(p0, 48)));
      const float q1 = ((p1 + __shfl_xor(p1, 16)) +
                        (__shfl_xor(p1, 32) + __shfl_xor(p1, 48)));
      kx = fmaf(-2.0f, q0, w3s0);   // k = sum(w3) + b3 - 2*q
      ky = fmaf(-2.0f, q1, w3s1);
    };

    EVAL(yx, yy, k1x, k1y);
    EVAL(fmaf(dt, A21 * k1x, yx), fmaf(dt, A21 * k1y, yy), k2x, k2y);
    {
      float cx = fmaf(A32, k2x, A31 * k1x);
      float cy = fmaf(A32, k2y, A31 * k1y);
      EVAL(fmaf(dt, cx, yx), fmaf(dt, cy, yy), k3x, k3y);
    }
    {
      float cx = fmaf(A43, k3x, fmaf(A42, k2x, A41 * k1x));
      float cy = fmaf(A43, k3y, fmaf(A42, k2y, A41 * k1y));
      EVAL(fmaf(dt, cx, yx), fmaf(dt, cy, yy), k4x, k4y);
    }
    {
      float cx = fmaf(A54, k4x, fmaf(A53, k3x, fmaf(A52, k2x, A51 * k1x)));
      float cy = fmaf(A54, k4y, fmaf(A53, k3y, fmaf(A52, k2y, A51 * k1y)));
      EVAL(fmaf(dt, cx, yx), fmaf(dt, cy, yy), k5x, k5y);
    }
    {
      float cx = fmaf(A65, k5x, fmaf(A64, k4x, fmaf(A63, k3x, fmaf(A62, k2x, A61 * k1x))));
      float cy = fmaf(A65, k5y, fmaf(A64, k4y, fmaf(A63, k3y, fmaf(A62, k2y, A61 * k1y))));
      EVAL(fmaf(dt, cx, yx), fmaf(dt, cy, yy), k6x, k6y);
    }
    {
      float cx = fmaf(BB6, k6x, fmaf(BB5, k5x, fmaf(BB4, k4x, fmaf(BB3, k3x, BB1 * k1x))));
      float cy = fmaf(BB6, k6y, fmaf(BB5, k5y, fmaf(BB4, k4y, fmaf(BB3, k3y, BB1 * k1y))));
      yx = fmaf(dt, cx, yx);
      yy = fmaf(dt, cy, yy);
    }
    if (quad == 0) outv[(t + 1) * NB + gb] = make_float2(yx, yy);
  }
}

extern "C" void kernel_launch(void* const* d_in, const int* in_sizes, int n_in,
                              void* d_out, int out_size, void* d_ws, size_t ws_size,
                              hipStream_t stream) {
  const float* y0 = (const float*)d_in[0];
  const float* ts = (const float*)d_in[1];
  const float* W1 = (const float*)d_in[2];
  const float* b1 = (const float*)d_in[3];
  const float* W2 = (const float*)d_in[4];
  const float* b2 = (const float*)d_in[5];
  const float* W3 = (const float*)d_in[6];
  const float* b3 = (const float*)d_in[7];
  float* out = (float*)d_out;

  // 256 blocks x 256 threads = 1024 waves (16 real cols each):
  // 1 wave/SIMD on all 256 CUs — proven-optimal geometry (r6 vs r8/r9).
  node_step_kernel<<<dim3(NB / 64), dim3(256), 0, stream>>>(
      y0, ts, W1, b1, W2, b2, W3, b3, out);
}